// Round 1
// 507.909 us; speedup vs baseline: 1.0869x; 1.0869x over previous
//
#include <hip/hip_runtime.h>
#include <cstdint>
#include <cstddef>

#define M_DIM 8192
#define N_DIM 4096
#define K_DIM 4096
#define CHUNK_M 4096   // x converted in 2 chunks of 33.5 MB so ws stays <= 67.1 MB

typedef __attribute__((ext_vector_type(8))) short bf16x8;
typedef __attribute__((ext_vector_type(4))) float floatx4;

__device__ __forceinline__ ushort f2bf_rne(float f) {
    union { float f; uint32_t u; } a;
    a.f = f;
    uint32_t u = a.u;
    uint32_t r = (u + 0x7fffu + ((u >> 16) & 1u)) >> 16;
    return (ushort)r;
}

// pack two fp32 into two bf16 (truncation), 1 instr
__device__ __forceinline__ uint32_t pk_bf_trunc(float f0, float f1) {
    return __builtin_amdgcn_perm(__float_as_uint(f1), __float_as_uint(f0),
                                 0x07060302u);
}

// ---------------------------------------------------------------------------
// Kernel 1: packed int4 (one signed byte per int32) -> dequant -> bf16 (RNE)
// ---------------------------------------------------------------------------
__global__ void dequant_w_kernel(const int4* __restrict__ pw,
                                 const float* __restrict__ scales,
                                 const float* __restrict__ zps,
                                 uint4* __restrict__ wb, int np4) {
    int p4 = blockIdx.x * blockDim.x + threadIdx.x;
    if (p4 >= np4) return;
    int p = p4 * 4;
    int g = p >> 18;
    float s = scales[g];
    float b = -zps[g] * s;
    int4 v = pw[p4];
    int vv[4] = { v.x, v.y, v.z, v.w };
    ushort o[8];
#pragma unroll
    for (int j = 0; j < 4; ++j) {
        int lo = ((int)((uint32_t)vv[j] << 28)) >> 28;
        int hi = ((int)((uint32_t)vv[j] << 24)) >> 28;
        o[2 * j]     = f2bf_rne(fmaf((float)lo, s, b));
        o[2 * j + 1] = f2bf_rne(fmaf((float)hi, s, b));
    }
    uint4 st;
    st.x = (uint32_t)o[0] | ((uint32_t)o[1] << 16);
    st.y = (uint32_t)o[2] | ((uint32_t)o[3] << 16);
    st.z = (uint32_t)o[4] | ((uint32_t)o[5] << 16);
    st.w = (uint32_t)o[6] | ((uint32_t)o[7] << 16);
    wb[p4] = st;
}

// ---------------------------------------------------------------------------
// Kernel 2: x fp32 -> bf16 (RNE), one chunk of CHUNK_M rows
// ---------------------------------------------------------------------------
__global__ void convert_x_kernel(const float4* __restrict__ x4,
                                 ushort4* __restrict__ out4, int n4) {
    int i = blockIdx.x * blockDim.x + threadIdx.x;
    if (i >= n4) return;
    float4 v = x4[i];
    ushort4 o;
    o.x = f2bf_rne(v.x);
    o.y = f2bf_rne(v.y);
    o.z = f2bf_rne(v.z);
    o.w = f2bf_rne(v.w);
    out4[i] = o;
}

// ---------------------------------------------------------------------------
// Kernel 3a: 256x256-tile deep-pipelined bf16 GEMM (T1+T3/T4+T5).
// A [Mc][K] bf16 row-major, B [N][K] bf16 row-major. C = A*B^T + bias.
// 512 threads = 8 waves (2M x 4N), per-wave 128x64 output, acc[8][4].
// BK=32 per K-step; ring of 4 LDS K-tile slots (128 KiB total):
//   iter t computes slot t&3, stages tile t+3 into slot (t+3)&3 (== slot of
//   tile t-1, fully read before the previous iteration's final barrier).
//   vmcnt(8) at iteration end == "tiles t+2,t+3 may be outstanding, tile t+1
//   landed" -> 3 K-tiles of prefetch depth, loads in flight across barriers.
// 2 phases/iter, each: 4-8 ds_read_b128 || 2 global_load_lds -> s_barrier ->
// lgkmcnt(0)+sched_barrier -> setprio(1) 16xMFMA setprio(0) -> s_barrier.
// ---------------------------------------------------------------------------
#define TBM 256
#define TBN 256
#define TBK 32
#define NT  (K_DIM / TBK)        // 128 K-steps
#define A_E 8192                 // elements of A per slot (256*32)
#define SLOT_E 16384             // elements per ring slot (A + B)

__global__ __launch_bounds__(512, 2)
void gemm_bf16_256(const ushort* __restrict__ A,
                   const ushort* __restrict__ B,
                   const float* __restrict__ bias,
                   float* __restrict__ C) {
    __shared__ ushort lds[4 * SLOT_E];   // 128 KiB -> 1 block/CU, 8 waves

    const int tid  = threadIdx.x;
    const int lane = tid & 63;
    const int wave = tid >> 6;
    const int wm   = wave >> 2;          // 0..1
    const int wn   = wave & 3;           // 0..3

    // T1: XCD-chunked bijective swizzle (nwg = 256, 256 % 8 == 0)
    const int nwg = gridDim.x;
    const int cpx = nwg >> 3;
    const int bid = blockIdx.x;
    const int swz = (bid & 7) * cpx + (bid >> 3);
    const int bn  = swz & (N_DIM / TBN - 1);
    const int bm  = swz / (N_DIM / TBN);

    const ushort* Ab = A + (size_t)(bm * TBM) * K_DIM;
    const ushort* Bb = B + (size_t)(bn * TBN) * K_DIM;

    // staging: thread tid covers LDS offset tid*16B of an 8KB part
    // -> part row tid>>2 (0..127), col bytes (tid&3)*16
    const int srow = tid >> 2;
    const int scol = (tid & 3) * 8;
    const ushort* gA0 = Ab + (size_t)srow * K_DIM + scol;
    const ushort* gA1 = gA0 + (size_t)128 * K_DIM;
    const ushort* gB0 = Bb + (size_t)srow * K_DIM + scol;
    const ushort* gB1 = gB0 + (size_t)128 * K_DIM;
    const int wdst = wave * 512;         // this wave's 1KB within a part

    // MFMA fragment addressing (same pattern as verified 128^2 kernel)
    const int frow = lane & 15;
    const int fcol = (lane >> 4) * 8;
    const int aoff = (wm * 128 + frow) * TBK + fcol;          // within A region
    const int boff = A_E + (wn * 64 + frow) * TBK + fcol;     // within B region

    floatx4 acc[8][4] = {};

#define STAGE_A(tt)                                                           \
    {                                                                          \
        const int k0s = ((tt) & (NT - 1)) * TBK;                               \
        ushort* d = lds + ((tt) & 3) * SLOT_E + wdst;                          \
        __builtin_amdgcn_global_load_lds(                                      \
            (const __attribute__((address_space(1))) void*)(gA0 + k0s),        \
            (__attribute__((address_space(3))) void*)d, 16, 0, 0);             \
        __builtin_amdgcn_global_load_lds(                                      \
            (const __attribute__((address_space(1))) void*)(gA1 + k0s),        \
            (__attribute__((address_space(3))) void*)(d + 4096), 16, 0, 0);    \
    }
#define STAGE_B(tt)                                                           \
    {                                                                          \
        const int k0s = ((tt) & (NT - 1)) * TBK;                               \
        ushort* d = lds + ((tt) & 3) * SLOT_E + A_E + wdst;                    \
        __builtin_amdgcn_global_load_lds(                                      \
            (const __attribute__((address_space(1))) void*)(gB0 + k0s),        \
            (__attribute__((address_space(3))) void*)d, 16, 0, 0);             \
        __builtin_amdgcn_global_load_lds(                                      \
            (const __attribute__((address_space(1))) void*)(gB1 + k0s),        \
            (__attribute__((address_space(3))) void*)(d + 4096), 16, 0, 0);    \
    }

    // prologue: tiles 0,1,2 in flight; vmcnt(8) -> tile 0 landed (1,2 may fly)
    STAGE_A(0) STAGE_B(0)
    STAGE_A(1) STAGE_B(1)
    STAGE_A(2) STAGE_B(2)
    asm volatile("s_waitcnt vmcnt(8)" ::: "memory");
    __builtin_amdgcn_s_barrier();
    __builtin_amdgcn_sched_barrier(0);

    for (int t = 0; t < NT; ++t) {
        const ushort* base = lds + (t & 3) * SLOT_E;

        // ---- phase A: B frags (all 4 cols) + A rows 0..3 ----
        bf16x8 bf[4], af[4];
#pragma unroll
        for (int j = 0; j < 4; ++j)
            bf[j] = *(const bf16x8*)(base + boff + j * 512);
#pragma unroll
        for (int i = 0; i < 4; ++i)
            af[i] = *(const bf16x8*)(base + aoff + i * 512);
        STAGE_A(t + 3)
        __builtin_amdgcn_s_barrier();
        asm volatile("s_waitcnt lgkmcnt(0)" ::: "memory");
        __builtin_amdgcn_sched_barrier(0);
        __builtin_amdgcn_s_setprio(1);
#pragma unroll
        for (int i = 0; i < 4; ++i)
#pragma unroll
            for (int j = 0; j < 4; ++j)
                acc[i][j] = __builtin_amdgcn_mfma_f32_16x16x32_bf16(
                    af[i], bf[j], acc[i][j], 0, 0, 0);
        __builtin_amdgcn_s_setprio(0);
        __builtin_amdgcn_s_barrier();
        __builtin_amdgcn_sched_barrier(0);

        // ---- phase B: A rows 4..7 (B frags held in regs) ----
#pragma unroll
        for (int i = 0; i < 4; ++i)
            af[i] = *(const bf16x8*)(base + aoff + (4 + i) * 512);
        STAGE_B(t + 3)
        __builtin_amdgcn_s_barrier();
        asm volatile("s_waitcnt lgkmcnt(0)" ::: "memory");
        __builtin_amdgcn_sched_barrier(0);
        __builtin_amdgcn_s_setprio(1);
#pragma unroll
        for (int i = 0; i < 4; ++i)
#pragma unroll
            for (int j = 0; j < 4; ++j)
                acc[4 + i][j] = __builtin_amdgcn_mfma_f32_16x16x32_bf16(
                    af[i], bf[j], acc[4 + i][j], 0, 0, 0);
        __builtin_amdgcn_s_setprio(0);
        // counted drain BEFORE the final barrier: tile t+1 landed, t+2/t+3 fly
        asm volatile("s_waitcnt vmcnt(8)" ::: "memory");
        __builtin_amdgcn_s_barrier();
        __builtin_amdgcn_sched_barrier(0);
    }
#undef STAGE_A
#undef STAGE_B

    // epilogue: C = acc + bias
    const int crow0 = bm * TBM + wm * 128;
    const int ccol0 = bn * TBN + wn * 64;
    const int rl = lane >> 4;
    const int cl = lane & 15;
#pragma unroll
    for (int j = 0; j < 4; ++j) {
        const int col = ccol0 + j * 16 + cl;
        const float bv = bias[col];
#pragma unroll
        for (int i = 0; i < 8; ++i) {
            const int row = crow0 + i * 16 + rl * 4;
            float* cp = C + (size_t)row * N_DIM + col;
#pragma unroll
            for (int r = 0; r < 4; ++r)
                cp[(size_t)r * N_DIM] = acc[i][j][r] + bv;
        }
    }
}

// ---------------------------------------------------------------------------
// Kernel 3b (fallback if ws too small): fused fp32-A GEMM, 128x128 tile.
// ---------------------------------------------------------------------------
#define BM 128
#define BN 128
#define BK 32

__global__ void gemm_fused_kernel(const float* __restrict__ X,
                                  const ushort* __restrict__ B,
                                  const float* __restrict__ bias,
                                  float* __restrict__ C) {
    __shared__ ushort As[BM * BK];
    __shared__ ushort Bs[BN * BK];

    const int tid  = threadIdx.x;
    const int lane = tid & 63;
    const int wave = tid >> 6;
    const int wm   = wave >> 1;
    const int wn   = wave & 1;
    const int bm   = blockIdx.y;
    const int bn   = blockIdx.x;

    const int ar = tid >> 2;          // 0..63
    const int ac = (tid & 3) * 8;     // k-offset (elements)
    const float* xp0 = X + (size_t)(bm * BM + ar) * K_DIM + ac;
    const float* xp1 = xp0 + (size_t)64 * K_DIM;
    ushort* as0 = As + ar * BK + ac;
    ushort* as1 = as0 + 64 * BK;

    const int scol = (lane & 3) * 8;
    const ushort* Bb = B + (size_t)(bn * BN) * K_DIM;

    floatx4 acc[4][4] = {};

    for (int k0 = 0; k0 < K_DIM; k0 += BK) {
        float4 a0 = *(const float4*)(xp0 + k0);
        float4 a1 = *(const float4*)(xp0 + k0 + 4);
        float4 b0 = *(const float4*)(xp1 + k0);
        float4 b1 = *(const float4*)(xp1 + k0 + 4);
#pragma unroll
        for (int q = 0; q < 2; ++q) {
            const int chunk = wave * 2 + q;
            const int r = chunk * 16 + (lane >> 2);
            const ushort* gb = Bb + (size_t)r * K_DIM + k0 + scol;
            __builtin_amdgcn_global_load_lds(
                (const __attribute__((address_space(1))) void*)gb,
                (__attribute__((address_space(3))) void*)(Bs + chunk * 512),
                16, 0, 0);
        }
        uint4 w0, w1;
        w0.x = pk_bf_trunc(a0.x, a0.y);
        w0.y = pk_bf_trunc(a0.z, a0.w);
        w0.z = pk_bf_trunc(a1.x, a1.y);
        w0.w = pk_bf_trunc(a1.z, a1.w);
        w1.x = pk_bf_trunc(b0.x, b0.y);
        w1.y = pk_bf_trunc(b0.z, b0.w);
        w1.z = pk_bf_trunc(b1.x, b1.y);
        w1.w = pk_bf_trunc(b1.z, b1.w);
        *(uint4*)as0 = w0;
        *(uint4*)as1 = w1;

        __syncthreads();

        bf16x8 af[4], bfr[4];
        const int frow = lane & 15;
        const int fcol = (lane >> 4) * 8;
#pragma unroll
        for (int i = 0; i < 4; ++i) {
            af[i]  = *(const bf16x8*)(As + (wm * 64 + i * 16 + frow) * BK + fcol);
            bfr[i] = *(const bf16x8*)(Bs + (wn * 64 + i * 16 + frow) * BK + fcol);
        }
#pragma unroll
        for (int i = 0; i < 4; ++i)
#pragma unroll
            for (int j = 0; j < 4; ++j)
                acc[i][j] = __builtin_amdgcn_mfma_f32_16x16x32_bf16(
                    af[i], bfr[j], acc[i][j], 0, 0, 0);
        __syncthreads();
    }

    const int crow0 = bm * BM + wm * 64;
    const int ccol0 = bn * BN + wn * 64;
    const int rl = lane >> 4;
    const int cl = lane & 15;
#pragma unroll
    for (int j = 0; j < 4; ++j) {
        const int col = ccol0 + j * 16 + cl;
        const float bv = bias[col];
#pragma unroll
        for (int i = 0; i < 4; ++i) {
            const int row = crow0 + i * 16 + rl * 4;
            float* cp = C + (size_t)row * N_DIM + col;
#pragma unroll
            for (int r = 0; r < 4; ++r)
                cp[(size_t)r * N_DIM] = acc[i][j][r] + bv;
        }
    }
}

// ---------------------------------------------------------------------------
extern "C" void kernel_launch(void* const* d_in, const int* in_sizes, int n_in,
                              void* d_out, int out_size, void* d_ws, size_t ws_size,
                              hipStream_t stream) {
    const float* x      = (const float*)d_in[0];
    const int*   pw     = (const int*)d_in[1];
    const float* scales = (const float*)d_in[2];
    const float* zps    = (const float*)d_in[3];
    const float* bias   = (const float*)d_in[4];
    float* out = (float*)d_out;

    ushort* wb = (ushort*)d_ws;                        // 33.5 MB

    {
        int np4 = (N_DIM * K_DIM / 2) / 4;
        dequant_w_kernel<<<np4 / 256, 256, 0, stream>>>(
            (const int4*)pw, scales, zps, (uint4*)wb, np4);
    }

    const size_t need = ((size_t)N_DIM * K_DIM + (size_t)CHUNK_M * K_DIM) * 2;
    if (ws_size >= need) {
        // pre-pass path: convert x chunk -> bf16 in ws, run 256^2 pipelined GEMM
        ushort* xb = wb + (size_t)N_DIM * K_DIM;       // 33.5 MB chunk buffer
        for (int c = 0; c < M_DIM / CHUNK_M; ++c) {
            const float* xc = x + (size_t)c * CHUNK_M * K_DIM;
            float* oc = out + (size_t)c * CHUNK_M * N_DIM;
            int n4 = (CHUNK_M * K_DIM) / 4;
            convert_x_kernel<<<n4 / 256, 256, 0, stream>>>(
                (const float4*)xc, (ushort4*)xb, n4);
            int nblk = (CHUNK_M / TBM) * (N_DIM / TBN);  // 16*16 = 256 = 1/CU
            gemm_bf16_256<<<nblk, 512, 0, stream>>>(xb, wb, bias, oc);
        }
    } else {
        // fallback: fused conversion with conflict-free LDS writes
        dim3 grid(N_DIM / BN, M_DIM / BM);             // (32, 64)
        gemm_fused_kernel<<<grid, 256, 0, stream>>>(x, wb, bias, out);
    }
}

// Round 2
// 483.821 us; speedup vs baseline: 1.1410x; 1.0498x over previous
//
#include <hip/hip_runtime.h>
#include <cstdint>
#include <cstddef>

#define M_DIM 8192
#define N_DIM 4096
#define K_DIM 4096
#define CHUNK_M 4096   // x converted in 2 chunks of 33.5 MB so ws stays <= 67.1 MB

typedef __attribute__((ext_vector_type(8))) short bf16x8;
typedef __attribute__((ext_vector_type(4))) float floatx4;

__device__ __forceinline__ ushort f2bf_rne(float f) {
    union { float f; uint32_t u; } a;
    a.f = f;
    uint32_t u = a.u;
    uint32_t r = (u + 0x7fffu + ((u >> 16) & 1u)) >> 16;
    return (ushort)r;
}

// pack two fp32 into two bf16 (truncation), 1 instr
__device__ __forceinline__ uint32_t pk_bf_trunc(float f0, float f1) {
    return __builtin_amdgcn_perm(__float_as_uint(f1), __float_as_uint(f0),
                                 0x07060302u);
}

// ---------------------------------------------------------------------------
// Kernel 1: packed int4 (one signed byte per int32) -> dequant -> bf16 (RNE)
// ---------------------------------------------------------------------------
__global__ void dequant_w_kernel(const int4* __restrict__ pw,
                                 const float* __restrict__ scales,
                                 const float* __restrict__ zps,
                                 uint4* __restrict__ wb, int np4) {
    int p4 = blockIdx.x * blockDim.x + threadIdx.x;
    if (p4 >= np4) return;
    int p = p4 * 4;
    int g = p >> 18;
    float s = scales[g];
    float b = -zps[g] * s;
    int4 v = pw[p4];
    int vv[4] = { v.x, v.y, v.z, v.w };
    ushort o[8];
#pragma unroll
    for (int j = 0; j < 4; ++j) {
        int lo = ((int)((uint32_t)vv[j] << 28)) >> 28;
        int hi = ((int)((uint32_t)vv[j] << 24)) >> 28;
        o[2 * j]     = f2bf_rne(fmaf((float)lo, s, b));
        o[2 * j + 1] = f2bf_rne(fmaf((float)hi, s, b));
    }
    uint4 st;
    st.x = (uint32_t)o[0] | ((uint32_t)o[1] << 16);
    st.y = (uint32_t)o[2] | ((uint32_t)o[3] << 16);
    st.z = (uint32_t)o[4] | ((uint32_t)o[5] << 16);
    st.w = (uint32_t)o[6] | ((uint32_t)o[7] << 16);
    wb[p4] = st;
}

// ---------------------------------------------------------------------------
// Kernel 2: x fp32 -> bf16 (RNE), one chunk of CHUNK_M rows
// ---------------------------------------------------------------------------
__global__ void convert_x_kernel(const float4* __restrict__ x4,
                                 ushort4* __restrict__ out4, int n4) {
    int i = blockIdx.x * blockDim.x + threadIdx.x;
    if (i >= n4) return;
    float4 v = x4[i];
    ushort4 o;
    o.x = f2bf_rne(v.x);
    o.y = f2bf_rne(v.y);
    o.z = f2bf_rne(v.z);
    o.w = f2bf_rne(v.w);
    out4[i] = o;
}

// ---------------------------------------------------------------------------
// Kernel 3a: 256x256-tile deep-pipelined bf16 GEMM (T1+T2+T3/T4+T5).
// A [Mc][K] bf16 row-major, B [N][K] bf16 row-major. C = A*B^T + bias.
// 512 threads = 8 waves (2M x 4N), per-wave 128x64 output, acc[8][4].
// Ring of 4 LDS K-tile slots; vmcnt(8) counted drain -> 3 tiles of prefetch.
//
// T2 swizzle (BK=32, rows are 64B = 4 x 16B slots): slot' = slot ^ ((row>>1)&3).
//   - global_load_lds dest stays LINEAR (HW requirement); the permutation is
//     applied by INVERSE-swizzling the per-lane GLOBAL source column
//     (staging thread tid fetches k-chunk (tid&3)^((tid>>3)&3)).
//   - fragment reads XOR the slot with ((frow>>1)&3). For every fragment row
//     wm*128 + i*16 + frow, (row>>1)&3 == (frow>>1)&3, so the XOR is a
//     per-lane constant and the i*512 additive offsets are unchanged.
//   Result: each 16-lane group covers all 8 bank-quads, 2 lanes/quad (free),
//   vs the un-swizzled 8-way conflict (2 quads, 8 lanes each).
// ---------------------------------------------------------------------------
#define TBM 256
#define TBN 256
#define TBK 32
#define NT  (K_DIM / TBK)        // 128 K-steps
#define A_E 8192                 // elements of A per slot (256*32)
#define SLOT_E 16384             // elements per ring slot (A + B)

__global__ __launch_bounds__(512, 2)
void gemm_bf16_256(const ushort* __restrict__ A,
                   const ushort* __restrict__ B,
                   const float* __restrict__ bias,
                   float* __restrict__ C) {
    __shared__ ushort lds[4 * SLOT_E];   // 128 KiB -> 1 block/CU, 8 waves

    const int tid  = threadIdx.x;
    const int lane = tid & 63;
    const int wave = tid >> 6;
    const int wm   = wave >> 2;          // 0..1
    const int wn   = wave & 3;           // 0..3

    // T1: XCD-chunked bijective swizzle (nwg = 256, 256 % 8 == 0)
    const int nwg = gridDim.x;
    const int cpx = nwg >> 3;
    const int bid = blockIdx.x;
    const int swz = (bid & 7) * cpx + (bid >> 3);
    const int bn  = swz & (N_DIM / TBN - 1);
    const int bm  = swz / (N_DIM / TBN);

    const ushort* Ab = A + (size_t)(bm * TBM) * K_DIM;
    const ushort* Bb = B + (size_t)(bn * TBN) * K_DIM;

    // staging: thread tid covers LDS offset tid*16B of an 8KB part
    // -> part row tid>>2 (0..127); T2: fetch INVERSE-swizzled global k-chunk
    const int srow = tid >> 2;
    const int scol = (((tid & 3) ^ ((tid >> 3) & 3)) * 8);
    const ushort* gA0 = Ab + (size_t)srow * K_DIM + scol;
    const ushort* gA1 = gA0 + (size_t)128 * K_DIM;
    const ushort* gB0 = Bb + (size_t)srow * K_DIM + scol;
    const ushort* gB1 = gB0 + (size_t)128 * K_DIM;
    const int wdst = wave * 512;         // this wave's 1KB within a part

    // MFMA fragment addressing: T2 swizzled slot, constant per lane
    const int frow = lane & 15;
    const int fcol = (((lane >> 4) ^ ((frow >> 1) & 3)) * 8);
    const int aoff = (wm * 128 + frow) * TBK + fcol;          // within A region
    const int boff = A_E + (wn * 64 + frow) * TBK + fcol;     // within B region

    floatx4 acc[8][4] = {};

#define STAGE_A(tt)                                                           \
    {                                                                          \
        const int k0s = ((tt) & (NT - 1)) * TBK;                               \
        ushort* d = lds + ((tt) & 3) * SLOT_E + wdst;                          \
        __builtin_amdgcn_global_load_lds(                                      \
            (const __attribute__((address_space(1))) void*)(gA0 + k0s),        \
            (__attribute__((address_space(3))) void*)d, 16, 0, 0);             \
        __builtin_amdgcn_global_load_lds(                                      \
            (const __attribute__((address_space(1))) void*)(gA1 + k0s),        \
            (__attribute__((address_space(3))) void*)(d + 4096), 16, 0, 0);    \
    }
#define STAGE_B(tt)                                                           \
    {                                                                          \
        const int k0s = ((tt) & (NT - 1)) * TBK;                               \
        ushort* d = lds + ((tt) & 3) * SLOT_E + A_E + wdst;                    \
        __builtin_amdgcn_global_load_lds(                                      \
            (const __attribute__((address_space(1))) void*)(gB0 + k0s),        \
            (__attribute__((address_space(3))) void*)d, 16, 0, 0);             \
        __builtin_amdgcn_global_load_lds(                                      \
            (const __attribute__((address_space(1))) void*)(gB1 + k0s),        \
            (__attribute__((address_space(3))) void*)(d + 4096), 16, 0, 0);    \
    }

    // prologue: tiles 0,1,2 in flight; vmcnt(8) -> tile 0 landed (1,2 may fly)
    STAGE_A(0) STAGE_B(0)
    STAGE_A(1) STAGE_B(1)
    STAGE_A(2) STAGE_B(2)
    asm volatile("s_waitcnt vmcnt(8)" ::: "memory");
    __builtin_amdgcn_s_barrier();
    __builtin_amdgcn_sched_barrier(0);

    for (int t = 0; t < NT; ++t) {
        const ushort* base = lds + (t & 3) * SLOT_E;

        // ---- phase A: B frags (all 4 cols) + A rows 0..3 ----
        bf16x8 bf[4], af[4];
#pragma unroll
        for (int j = 0; j < 4; ++j)
            bf[j] = *(const bf16x8*)(base + boff + j * 512);
#pragma unroll
        for (int i = 0; i < 4; ++i)
            af[i] = *(const bf16x8*)(base + aoff + i * 512);
        STAGE_A(t + 3)
        __builtin_amdgcn_s_barrier();
        asm volatile("s_waitcnt lgkmcnt(0)" ::: "memory");
        __builtin_amdgcn_sched_barrier(0);
        __builtin_amdgcn_s_setprio(1);
#pragma unroll
        for (int i = 0; i < 4; ++i)
#pragma unroll
            for (int j = 0; j < 4; ++j)
                acc[i][j] = __builtin_amdgcn_mfma_f32_16x16x32_bf16(
                    af[i], bf[j], acc[i][j], 0, 0, 0);
        __builtin_amdgcn_s_setprio(0);
        __builtin_amdgcn_s_barrier();
        __builtin_amdgcn_sched_barrier(0);

        // ---- phase B: A rows 4..7 (B frags held in regs) ----
#pragma unroll
        for (int i = 0; i < 4; ++i)
            af[i] = *(const bf16x8*)(base + aoff + (4 + i) * 512);
        STAGE_B(t + 3)
        __builtin_amdgcn_s_barrier();
        asm volatile("s_waitcnt lgkmcnt(0)" ::: "memory");
        __builtin_amdgcn_sched_barrier(0);
        __builtin_amdgcn_s_setprio(1);
#pragma unroll
        for (int i = 0; i < 4; ++i)
#pragma unroll
            for (int j = 0; j < 4; ++j)
                acc[4 + i][j] = __builtin_amdgcn_mfma_f32_16x16x32_bf16(
                    af[i], bf[j], acc[4 + i][j], 0, 0, 0);
        __builtin_amdgcn_s_setprio(0);
        // counted drain BEFORE the final barrier: tile t+1 landed, t+2/t+3 fly
        asm volatile("s_waitcnt vmcnt(8)" ::: "memory");
        __builtin_amdgcn_s_barrier();
        __builtin_amdgcn_sched_barrier(0);
    }
#undef STAGE_A
#undef STAGE_B

    // epilogue: C = acc + bias
    const int crow0 = bm * TBM + wm * 128;
    const int ccol0 = bn * TBN + wn * 64;
    const int rl = lane >> 4;
    const int cl = lane & 15;
#pragma unroll
    for (int j = 0; j < 4; ++j) {
        const int col = ccol0 + j * 16 + cl;
        const float bv = bias[col];
#pragma unroll
        for (int i = 0; i < 8; ++i) {
            const int row = crow0 + i * 16 + rl * 4;
            float* cp = C + (size_t)row * N_DIM + col;
#pragma unroll
            for (int r = 0; r < 4; ++r)
                cp[(size_t)r * N_DIM] = acc[i][j][r] + bv;
        }
    }
}

// ---------------------------------------------------------------------------
// Kernel 3b (fallback if ws too small): fused fp32-A GEMM, 128x128 tile.
// (unchanged / unswizzled — not exercised when ws suffices)
// ---------------------------------------------------------------------------
#define BM 128
#define BN 128
#define BK 32

__global__ void gemm_fused_kernel(const float* __restrict__ X,
                                  const ushort* __restrict__ B,
                                  const float* __restrict__ bias,
                                  float* __restrict__ C) {
    __shared__ ushort As[BM * BK];
    __shared__ ushort Bs[BN * BK];

    const int tid  = threadIdx.x;
    const int lane = tid & 63;
    const int wave = tid >> 6;
    const int wm   = wave >> 1;
    const int wn   = wave & 1;
    const int bm   = blockIdx.y;
    const int bn   = blockIdx.x;

    const int ar = tid >> 2;          // 0..63
    const int ac = (tid & 3) * 8;     // k-offset (elements)
    const float* xp0 = X + (size_t)(bm * BM + ar) * K_DIM + ac;
    const float* xp1 = xp0 + (size_t)64 * K_DIM;
    ushort* as0 = As + ar * BK + ac;
    ushort* as1 = as0 + 64 * BK;

    const int scol = (lane & 3) * 8;
    const ushort* Bb = B + (size_t)(bn * BN) * K_DIM;

    floatx4 acc[4][4] = {};

    for (int k0 = 0; k0 < K_DIM; k0 += BK) {
        float4 a0 = *(const float4*)(xp0 + k0);
        float4 a1 = *(const float4*)(xp0 + k0 + 4);
        float4 b0 = *(const float4*)(xp1 + k0);
        float4 b1 = *(const float4*)(xp1 + k0 + 4);
#pragma unroll
        for (int q = 0; q < 2; ++q) {
            const int chunk = wave * 2 + q;
            const int r = chunk * 16 + (lane >> 2);
            const ushort* gb = Bb + (size_t)r * K_DIM + k0 + scol;
            __builtin_amdgcn_global_load_lds(
                (const __attribute__((address_space(1))) void*)gb,
                (__attribute__((address_space(3))) void*)(Bs + chunk * 512),
                16, 0, 0);
        }
        uint4 w0, w1;
        w0.x = pk_bf_trunc(a0.x, a0.y);
        w0.y = pk_bf_trunc(a0.z, a0.w);
        w0.z = pk_bf_trunc(a1.x, a1.y);
        w0.w = pk_bf_trunc(a1.z, a1.w);
        w1.x = pk_bf_trunc(b0.x, b0.y);
        w1.y = pk_bf_trunc(b0.z, b0.w);
        w1.z = pk_bf_trunc(b1.x, b1.y);
        w1.w = pk_bf_trunc(b1.z, b1.w);
        *(uint4*)as0 = w0;
        *(uint4*)as1 = w1;

        __syncthreads();

        bf16x8 af[4], bfr[4];
        const int frow = lane & 15;
        const int fcol = (lane >> 4) * 8;
#pragma unroll
        for (int i = 0; i < 4; ++i) {
            af[i]  = *(const bf16x8*)(As + (wm * 64 + i * 16 + frow) * BK + fcol);
            bfr[i] = *(const bf16x8*)(Bs + (wn * 64 + i * 16 + frow) * BK + fcol);
        }
#pragma unroll
        for (int i = 0; i < 4; ++i)
#pragma unroll
            for (int j = 0; j < 4; ++j)
                acc[i][j] = __builtin_amdgcn_mfma_f32_16x16x32_bf16(
                    af[i], bfr[j], acc[i][j], 0, 0, 0);
        __syncthreads();
    }

    const int crow0 = bm * BM + wm * 64;
    const int ccol0 = bn * BN + wn * 64;
    const int rl = lane >> 4;
    const int cl = lane & 15;
#pragma unroll
    for (int j = 0; j < 4; ++j) {
        const int col = ccol0 + j * 16 + cl;
        const float bv = bias[col];
#pragma unroll
        for (int i = 0; i < 4; ++i) {
            const int row = crow0 + i * 16 + rl * 4;
            float* cp = C + (size_t)row * N_DIM + col;
#pragma unroll
            for (int r = 0; r < 4; ++r)
                cp[(size_t)r * N_DIM] = acc[i][j][r] + bv;
        }
    }
}

// ---------------------------------------------------------------------------
extern "C" void kernel_launch(void* const* d_in, const int* in_sizes, int n_in,
                              void* d_out, int out_size, void* d_ws, size_t ws_size,
                              hipStream_t stream) {
    const float* x      = (const float*)d_in[0];
    const int*   pw     = (const int*)d_in[1];
    const float* scales = (const float*)d_in[2];
    const float* zps    = (const float*)d_in[3];
    const float* bias   = (const float*)d_in[4];
    float* out = (float*)d_out;

    ushort* wb = (ushort*)d_ws;                        // 33.5 MB

    {
        int np4 = (N_DIM * K_DIM / 2) / 4;
        dequant_w_kernel<<<np4 / 256, 256, 0, stream>>>(
            (const int4*)pw, scales, zps, (uint4*)wb, np4);
    }

    const size_t need = ((size_t)N_DIM * K_DIM + (size_t)CHUNK_M * K_DIM) * 2;
    if (ws_size >= need) {
        // pre-pass path: convert x chunk -> bf16 in ws, run 256^2 pipelined GEMM
        ushort* xb = wb + (size_t)N_DIM * K_DIM;       // 33.5 MB chunk buffer
        for (int c = 0; c < M_DIM / CHUNK_M; ++c) {
            const float* xc = x + (size_t)c * CHUNK_M * K_DIM;
            float* oc = out + (size_t)c * CHUNK_M * N_DIM;
            int n4 = (CHUNK_M * K_DIM) / 4;
            convert_x_kernel<<<n4 / 256, 256, 0, stream>>>(
                (const float4*)xc, (ushort4*)xb, n4);
            int nblk = (CHUNK_M / TBM) * (N_DIM / TBN);  // 16*16 = 256 = 1/CU
            gemm_bf16_256<<<nblk, 512, 0, stream>>>(xb, wb, bias, oc);
        }
    } else {
        // fallback: fused conversion with conflict-free LDS writes
        dim3 grid(N_DIM / BN, M_DIM / BM);             // (32, 64)
        gemm_fused_kernel<<<grid, 256, 0, stream>>>(x, wb, bias, out);
    }
}

// Round 3
// 472.513 us; speedup vs baseline: 1.1683x; 1.0239x over previous
//
#include <hip/hip_runtime.h>
#include <cstdint>
#include <cstddef>

#define M_DIM 8192
#define N_DIM 4096
#define K_DIM 4096
#define CHUNK_M 4096   // chunked fallback if ws can't hold full converted x

typedef __attribute__((ext_vector_type(8))) short bf16x8;
typedef __attribute__((ext_vector_type(4))) float floatx4;

__device__ __forceinline__ ushort f2bf_rne(float f) {
    union { float f; uint32_t u; } a;
    a.f = f;
    uint32_t u = a.u;
    uint32_t r = (u + 0x7fffu + ((u >> 16) & 1u)) >> 16;
    return (ushort)r;
}

// pack two fp32 into two bf16 (truncation), 1 instr
__device__ __forceinline__ uint32_t pk_bf_trunc(float f0, float f1) {
    return __builtin_amdgcn_perm(__float_as_uint(f1), __float_as_uint(f0),
                                 0x07060302u);
}

// ---------------------------------------------------------------------------
// Kernel 1: packed int4 (one signed byte per int32) -> dequant -> bf16 (RNE)
// ---------------------------------------------------------------------------
__global__ void dequant_w_kernel(const int4* __restrict__ pw,
                                 const float* __restrict__ scales,
                                 const float* __restrict__ zps,
                                 uint4* __restrict__ wb, int np4) {
    int p4 = blockIdx.x * blockDim.x + threadIdx.x;
    if (p4 >= np4) return;
    int p = p4 * 4;
    int g = p >> 18;
    float s = scales[g];
    float b = -zps[g] * s;
    int4 v = pw[p4];
    int vv[4] = { v.x, v.y, v.z, v.w };
    ushort o[8];
#pragma unroll
    for (int j = 0; j < 4; ++j) {
        int lo = ((int)((uint32_t)vv[j] << 28)) >> 28;
        int hi = ((int)((uint32_t)vv[j] << 24)) >> 28;
        o[2 * j]     = f2bf_rne(fmaf((float)lo, s, b));
        o[2 * j + 1] = f2bf_rne(fmaf((float)hi, s, b));
    }
    uint4 st;
    st.x = (uint32_t)o[0] | ((uint32_t)o[1] << 16);
    st.y = (uint32_t)o[2] | ((uint32_t)o[3] << 16);
    st.z = (uint32_t)o[4] | ((uint32_t)o[5] << 16);
    st.w = (uint32_t)o[6] | ((uint32_t)o[7] << 16);
    wb[p4] = st;
}

// ---------------------------------------------------------------------------
// Kernel 2: x fp32 -> bf16 (RNE)
// ---------------------------------------------------------------------------
__global__ void convert_x_kernel(const float4* __restrict__ x4,
                                 ushort4* __restrict__ out4, int n4) {
    int i = blockIdx.x * blockDim.x + threadIdx.x;
    if (i >= n4) return;
    float4 v = x4[i];
    ushort4 o;
    o.x = f2bf_rne(v.x);
    o.y = f2bf_rne(v.y);
    o.z = f2bf_rne(v.z);
    o.w = f2bf_rne(v.w);
    out4[i] = o;
}

// ---------------------------------------------------------------------------
// Kernel 3a: 256x256-tile pipelined bf16 GEMM (T1+T2+T4+T5 + frag-dbuf).
// A [M][K] bf16 row-major, B [N][K] bf16 row-major. C = A*B^T + bias.
// 512 threads = 8 waves (2M x 4N), per-wave 128x64 output, acc[8][4].
//
// Schedule (ONE barrier + ONE counted vmcnt per K-step; no lgkmcnt(0)):
//   iter t enters with frags afc(t rows0-3), bfc(t) in regs.
//   1. STAGE tile t+3 into slot (t+3)&3 (= slot of tile t-1; freed by beta(t-1))
//   2. ds_read afb = A rows4-7 of tile t            (awaited by compiler @ MFMA-B)
//   3. MFMA phase A (acc[0..3] += afc x bfc)        (LDS reads #2 fly underneath)
//   4. ds_read afn/bfn = tile t+1 frags             (slot landed per beta(t-1))
//   5. MFMA phase B (acc[4..7] += afb x bfc)        (LDS reads #4 fly underneath)
//   6. vmcnt(4): own tile-t+2 loads landed (t+3's 4 may fly) -> beta(t) barrier.
// Invariant beta(t): all waves done reading tile t; all tile-t+2 stages landed.
// Hazard check: afn(t+1) reads complete before MFMA-A(t+1) < beta(t+1); their
// slot is re-staged only at iter t+2 (after beta(t+1)) -> no WAR race.
//
// T2 swizzle (BK=32, rows = 4 x 16B slots): slot' = slot ^ ((row>>1)&3),
// applied as inverse-swizzled GLOBAL source (LDS dest stays linear for
// global_load_lds) + swizzled fragment-read address (per-lane constant).
// ---------------------------------------------------------------------------
#define TBM 256
#define TBN 256
#define TBK 32
#define NT  (K_DIM / TBK)        // 128 K-steps
#define A_E 8192                 // elements of A per slot (256*32)
#define SLOT_E 16384             // elements per ring slot (A + B)

__global__ __launch_bounds__(512, 2)
void gemm_bf16_256(const ushort* __restrict__ A,
                   const ushort* __restrict__ B,
                   const float* __restrict__ bias,
                   float* __restrict__ C) {
    __shared__ ushort lds[4 * SLOT_E];   // 128 KiB -> 1 block/CU, 8 waves

    const int tid  = threadIdx.x;
    const int lane = tid & 63;
    const int wave = tid >> 6;
    const int wm   = wave >> 2;          // 0..1
    const int wn   = wave & 3;           // 0..3

    // T1: XCD-chunked bijective swizzle (nwg % 8 == 0 for both 256 and 512)
    const int nwg = gridDim.x;
    const int cpx = nwg >> 3;
    const int bid = blockIdx.x;
    const int swz = (bid & 7) * cpx + (bid >> 3);
    const int bn  = swz & (N_DIM / TBN - 1);
    const int bm  = swz / (N_DIM / TBN);

    const ushort* Ab = A + (size_t)(bm * TBM) * K_DIM;
    const ushort* Bb = B + (size_t)(bn * TBN) * K_DIM;

    // staging: thread tid covers LDS offset tid*16B of an 8KB part
    // -> part row tid>>2 (0..127); T2: fetch INVERSE-swizzled global k-chunk
    const int srow = tid >> 2;
    const int scol = (((tid & 3) ^ ((tid >> 3) & 3)) * 8);
    const ushort* gA0 = Ab + (size_t)srow * K_DIM + scol;
    const ushort* gA1 = gA0 + (size_t)128 * K_DIM;
    const ushort* gB0 = Bb + (size_t)srow * K_DIM + scol;
    const ushort* gB1 = gB0 + (size_t)128 * K_DIM;
    const int wdst = wave * 512;         // this wave's 1KB within a part

    // MFMA fragment addressing: T2 swizzled slot, constant per lane
    const int frow = lane & 15;
    const int fcol = (((lane >> 4) ^ ((frow >> 1) & 3)) * 8);
    const int aoff = (wm * 128 + frow) * TBK + fcol;          // within A region
    const int boff = A_E + (wn * 64 + frow) * TBK + fcol;     // within B region

    floatx4 acc[8][4] = {};

#define STAGE_A(tt)                                                           \
    {                                                                          \
        const int k0s = ((tt) & (NT - 1)) * TBK;                               \
        ushort* d = lds + ((tt) & 3) * SLOT_E + wdst;                          \
        __builtin_amdgcn_global_load_lds(                                      \
            (const __attribute__((address_space(1))) void*)(gA0 + k0s),        \
            (__attribute__((address_space(3))) void*)d, 16, 0, 0);             \
        __builtin_amdgcn_global_load_lds(                                      \
            (const __attribute__((address_space(1))) void*)(gA1 + k0s),        \
            (__attribute__((address_space(3))) void*)(d + 4096), 16, 0, 0);    \
    }
#define STAGE_B(tt)                                                           \
    {                                                                          \
        const int k0s = ((tt) & (NT - 1)) * TBK;                               \
        ushort* d = lds + ((tt) & 3) * SLOT_E + A_E + wdst;                    \
        __builtin_amdgcn_global_load_lds(                                      \
            (const __attribute__((address_space(1))) void*)(gB0 + k0s),        \
            (__attribute__((address_space(3))) void*)d, 16, 0, 0);             \
        __builtin_amdgcn_global_load_lds(                                      \
            (const __attribute__((address_space(1))) void*)(gB1 + k0s),        \
            (__attribute__((address_space(3))) void*)(d + 4096), 16, 0, 0);    \
    }

// one K-step; afc/bfc = current frags (consumed), afn/bfn = next frags (filled)
#define BODY(T, afc, bfc, afn, bfn)                                           \
    {                                                                          \
        STAGE_A((T) + 3) STAGE_B((T) + 3)                                      \
        const ushort* bcur = lds + ((T) & 3) * SLOT_E;                         \
        const ushort* bnxt = lds + (((T) + 1) & 3) * SLOT_E;                   \
        bf16x8 afb[4];                                                         \
        _Pragma("unroll")                                                      \
        for (int i = 0; i < 4; ++i)                                            \
            afb[i] = *(const bf16x8*)(bcur + aoff + (4 + i) * 512);            \
        __builtin_amdgcn_s_setprio(1);                                         \
        _Pragma("unroll")                                                      \
        for (int i = 0; i < 4; ++i)                                            \
            _Pragma("unroll")                                                  \
            for (int j = 0; j < 4; ++j)                                        \
                acc[i][j] = __builtin_amdgcn_mfma_f32_16x16x32_bf16(           \
                    afc[i], bfc[j], acc[i][j], 0, 0, 0);                       \
        __builtin_amdgcn_s_setprio(0);                                         \
        _Pragma("unroll")                                                      \
        for (int j = 0; j < 4; ++j)                                            \
            bfn[j] = *(const bf16x8*)(bnxt + boff + j * 512);                  \
        _Pragma("unroll")                                                      \
        for (int i = 0; i < 4; ++i)                                            \
            afn[i] = *(const bf16x8*)(bnxt + aoff + i * 512);                  \
        __builtin_amdgcn_s_setprio(1);                                         \
        _Pragma("unroll")                                                      \
        for (int i = 0; i < 4; ++i)                                            \
            _Pragma("unroll")                                                  \
            for (int j = 0; j < 4; ++j)                                        \
                acc[4 + i][j] = __builtin_amdgcn_mfma_f32_16x16x32_bf16(       \
                    afb[i], bfc[j], acc[4 + i][j], 0, 0, 0);                   \
        __builtin_amdgcn_s_setprio(0);                                         \
        asm volatile("s_waitcnt vmcnt(4)" ::: "memory");                       \
        __builtin_amdgcn_s_barrier();                                          \
        __builtin_amdgcn_sched_barrier(0);                                     \
    }

    // prologue: tiles 0,1,2 in flight; vmcnt(4) -> tiles 0,1 landed (2 flying)
    STAGE_A(0) STAGE_B(0)
    STAGE_A(1) STAGE_B(1)
    STAGE_A(2) STAGE_B(2)
    asm volatile("s_waitcnt vmcnt(4)" ::: "memory");
    __builtin_amdgcn_s_barrier();
    __builtin_amdgcn_sched_barrier(0);

    bf16x8 af0[4], bf0[4], af1[4], bf1[4];
#pragma unroll
    for (int j = 0; j < 4; ++j)
        bf0[j] = *(const bf16x8*)(lds + boff + j * 512);
#pragma unroll
    for (int i = 0; i < 4; ++i)
        af0[i] = *(const bf16x8*)(lds + aoff + i * 512);

    for (int t = 0; t < NT; t += 2) {
        BODY(t,     af0, bf0, af1, bf1)
        BODY(t + 1, af1, bf1, af0, bf0)
    }
#undef BODY
#undef STAGE_A
#undef STAGE_B

    // epilogue: C = acc + bias
    const int crow0 = bm * TBM + wm * 128;
    const int ccol0 = bn * TBN + wn * 64;
    const int rl = lane >> 4;
    const int cl = lane & 15;
#pragma unroll
    for (int j = 0; j < 4; ++j) {
        const int col = ccol0 + j * 16 + cl;
        const float bv = bias[col];
#pragma unroll
        for (int i = 0; i < 8; ++i) {
            const int row = crow0 + i * 16 + rl * 4;
            float* cp = C + (size_t)row * N_DIM + col;
#pragma unroll
            for (int r = 0; r < 4; ++r)
                cp[(size_t)r * N_DIM] = acc[i][j][r] + bv;
        }
    }
}

// ---------------------------------------------------------------------------
// Kernel 3b (fallback if ws too small): fused fp32-A GEMM, 128x128 tile.
// ---------------------------------------------------------------------------
#define BM 128
#define BN 128
#define BK 32

__global__ void gemm_fused_kernel(const float* __restrict__ X,
                                  const ushort* __restrict__ B,
                                  const float* __restrict__ bias,
                                  float* __restrict__ C) {
    __shared__ ushort As[BM * BK];
    __shared__ ushort Bs[BN * BK];

    const int tid  = threadIdx.x;
    const int lane = tid & 63;
    const int wave = tid >> 6;
    const int wm   = wave >> 1;
    const int wn   = wave & 1;
    const int bm   = blockIdx.y;
    const int bn   = blockIdx.x;

    const int ar = tid >> 2;          // 0..63
    const int ac = (tid & 3) * 8;     // k-offset (elements)
    const float* xp0 = X + (size_t)(bm * BM + ar) * K_DIM + ac;
    const float* xp1 = xp0 + (size_t)64 * K_DIM;
    ushort* as0 = As + ar * BK + ac;
    ushort* as1 = as0 + 64 * BK;

    const int scol = (lane & 3) * 8;
    const ushort* Bb = B + (size_t)(bn * BN) * K_DIM;

    floatx4 acc[4][4] = {};

    for (int k0 = 0; k0 < K_DIM; k0 += BK) {
        float4 a0 = *(const float4*)(xp0 + k0);
        float4 a1 = *(const float4*)(xp0 + k0 + 4);
        float4 b0 = *(const float4*)(xp1 + k0);
        float4 b1 = *(const float4*)(xp1 + k0 + 4);
#pragma unroll
        for (int q = 0; q < 2; ++q) {
            const int chunk = wave * 2 + q;
            const int r = chunk * 16 + (lane >> 2);
            const ushort* gb = Bb + (size_t)r * K_DIM + k0 + scol;
            __builtin_amdgcn_global_load_lds(
                (const __attribute__((address_space(1))) void*)gb,
                (__attribute__((address_space(3))) void*)(Bs + chunk * 512),
                16, 0, 0);
        }
        uint4 w0, w1;
        w0.x = pk_bf_trunc(a0.x, a0.y);
        w0.y = pk_bf_trunc(a0.z, a0.w);
        w0.z = pk_bf_trunc(a1.x, a1.y);
        w0.w = pk_bf_trunc(a1.z, a1.w);
        w1.x = pk_bf_trunc(b0.x, b0.y);
        w1.y = pk_bf_trunc(b0.z, b0.w);
        w1.z = pk_bf_trunc(b1.x, b1.y);
        w1.w = pk_bf_trunc(b1.z, b1.w);
        *(uint4*)as0 = w0;
        *(uint4*)as1 = w1;

        __syncthreads();

        bf16x8 af[4], bfr[4];
        const int frow = lane & 15;
        const int fcol = (lane >> 4) * 8;
#pragma unroll
        for (int i = 0; i < 4; ++i) {
            af[i]  = *(const bf16x8*)(As + (wm * 64 + i * 16 + frow) * BK + fcol);
            bfr[i] = *(const bf16x8*)(Bs + (wn * 64 + i * 16 + frow) * BK + fcol);
        }
#pragma unroll
        for (int i = 0; i < 4; ++i)
#pragma unroll
            for (int j = 0; j < 4; ++j)
                acc[i][j] = __builtin_amdgcn_mfma_f32_16x16x32_bf16(
                    af[i], bfr[j], acc[i][j], 0, 0, 0);
        __syncthreads();
    }

    const int crow0 = bm * BM + wm * 64;
    const int ccol0 = bn * BN + wn * 64;
    const int rl = lane >> 4;
    const int cl = lane & 15;
#pragma unroll
    for (int j = 0; j < 4; ++j) {
        const int col = ccol0 + j * 16 + cl;
        const float bv = bias[col];
#pragma unroll
        for (int i = 0; i < 4; ++i) {
            const int row = crow0 + i * 16 + rl * 4;
            float* cp = C + (size_t)row * N_DIM + col;
#pragma unroll
            for (int r = 0; r < 4; ++r)
                cp[(size_t)r * N_DIM] = acc[i][j][r] + bv;
        }
    }
}

// ---------------------------------------------------------------------------
extern "C" void kernel_launch(void* const* d_in, const int* in_sizes, int n_in,
                              void* d_out, int out_size, void* d_ws, size_t ws_size,
                              hipStream_t stream) {
    const float* x      = (const float*)d_in[0];
    const int*   pw     = (const int*)d_in[1];
    const float* scales = (const float*)d_in[2];
    const float* zps    = (const float*)d_in[3];
    const float* bias   = (const float*)d_in[4];
    float* out = (float*)d_out;

    ushort* wb = (ushort*)d_ws;                        // 33.5 MB

    {
        int np4 = (N_DIM * K_DIM / 2) / 4;
        dequant_w_kernel<<<np4 / 256, 256, 0, stream>>>(
            (const int4*)pw, scales, zps, (uint4*)wb, np4);
    }

    const size_t need_full  = ((size_t)N_DIM * K_DIM + (size_t)M_DIM * K_DIM) * 2;
    const size_t need_chunk = ((size_t)N_DIM * K_DIM + (size_t)CHUNK_M * K_DIM) * 2;

    if (ws_size >= need_full) {
        // full path: convert all of x once, single GEMM over M=8192
        ushort* xb = wb + (size_t)N_DIM * K_DIM;       // 67.1 MB
        int n4 = (M_DIM * K_DIM) / 4;
        convert_x_kernel<<<n4 / 256, 256, 0, stream>>>(
            (const float4*)x, (ushort4*)xb, n4);
        int nblk = (M_DIM / TBM) * (N_DIM / TBN);      // 32*16 = 512
        gemm_bf16_256<<<nblk, 512, 0, stream>>>(xb, wb, bias, out);
    } else if (ws_size >= need_chunk) {
        // chunked path: convert x chunk -> bf16 in ws, GEMM per chunk
        ushort* xb = wb + (size_t)N_DIM * K_DIM;       // 33.5 MB chunk buffer
        for (int c = 0; c < M_DIM / CHUNK_M; ++c) {
            const float* xc = x + (size_t)c * CHUNK_M * K_DIM;
            float* oc = out + (size_t)c * CHUNK_M * N_DIM;
            int n4 = (CHUNK_M * K_DIM) / 4;
            convert_x_kernel<<<n4 / 256, 256, 0, stream>>>(
                (const float4*)xc, (ushort4*)xb, n4);
            int nblk = (CHUNK_M / TBM) * (N_DIM / TBN);  // 16*16 = 256
            gemm_bf16_256<<<nblk, 512, 0, stream>>>(xb, wb, bias, oc);
        }
    } else {
        // fallback: fused conversion with conflict-free LDS writes
        dim3 grid(N_DIM / BN, M_DIM / BM);             // (32, 64)
        gemm_fused_kernel<<<grid, 256, 0, stream>>>(x, wb, bias, out);
    }
}

// Round 4
// 471.976 us; speedup vs baseline: 1.1697x; 1.0011x over previous
//
#include <hip/hip_runtime.h>
#include <cstdint>
#include <cstddef>

#define M_DIM 8192
#define N_DIM 4096
#define K_DIM 4096
#define CHUNK_M 4096   // chunked fallback if ws can't hold full converted x

typedef __attribute__((ext_vector_type(8))) short bf16x8;
typedef __attribute__((ext_vector_type(4))) float floatx4;

__device__ __forceinline__ ushort f2bf_rne(float f) {
    union { float f; uint32_t u; } a;
    a.f = f;
    uint32_t u = a.u;
    uint32_t r = (u + 0x7fffu + ((u >> 16) & 1u)) >> 16;
    return (ushort)r;
}

// pack two fp32 into two bf16 (truncation), 1 instr
__device__ __forceinline__ uint32_t pk_bf_trunc(float f0, float f1) {
    return __builtin_amdgcn_perm(__float_as_uint(f1), __float_as_uint(f0),
                                 0x07060302u);
}

// ---------------------------------------------------------------------------
// Kernel 1: packed int4 (one signed byte per int32) -> dequant -> bf16 (RNE)
// ---------------------------------------------------------------------------
__global__ void dequant_w_kernel(const int4* __restrict__ pw,
                                 const float* __restrict__ scales,
                                 const float* __restrict__ zps,
                                 uint4* __restrict__ wb, int np4) {
    int p4 = blockIdx.x * blockDim.x + threadIdx.x;
    if (p4 >= np4) return;
    int p = p4 * 4;
    int g = p >> 18;
    float s = scales[g];
    float b = -zps[g] * s;
    int4 v = pw[p4];
    int vv[4] = { v.x, v.y, v.z, v.w };
    ushort o[8];
#pragma unroll
    for (int j = 0; j < 4; ++j) {
        int lo = ((int)((uint32_t)vv[j] << 28)) >> 28;
        int hi = ((int)((uint32_t)vv[j] << 24)) >> 28;
        o[2 * j]     = f2bf_rne(fmaf((float)lo, s, b));
        o[2 * j + 1] = f2bf_rne(fmaf((float)hi, s, b));
    }
    uint4 st;
    st.x = (uint32_t)o[0] | ((uint32_t)o[1] << 16);
    st.y = (uint32_t)o[2] | ((uint32_t)o[3] << 16);
    st.z = (uint32_t)o[4] | ((uint32_t)o[5] << 16);
    st.w = (uint32_t)o[6] | ((uint32_t)o[7] << 16);
    wb[p4] = st;
}

// ---------------------------------------------------------------------------
// Kernel 2: x fp32 -> bf16 (RNE)
// ---------------------------------------------------------------------------
__global__ void convert_x_kernel(const float4* __restrict__ x4,
                                 ushort4* __restrict__ out4, int n4) {
    int i = blockIdx.x * blockDim.x + threadIdx.x;
    if (i >= n4) return;
    float4 v = x4[i];
    ushort4 o;
    o.x = f2bf_rne(v.x);
    o.y = f2bf_rne(v.y);
    o.z = f2bf_rne(v.z);
    o.w = f2bf_rne(v.w);
    out4[i] = o;
}

// ---------------------------------------------------------------------------
// Kernel 3a: 256x256-tile pipelined bf16 GEMM (T1+T2+T4+T5 + frag-dbuf).
// A [M][K] bf16 row-major, B [N][K] bf16 row-major. C = A*B^T + bias.
// 512 threads = 8 waves (2M x 4N), per-wave 128x64 output, acc[8][4].
//
// R4 schedule: ALL 12 ds_read_b128 issued at step top (afb + next-tile
// afn/bfn), THEN one 32-MFMA cluster. sched_barrier(0) pins the loads above
// the MFMAs; the compiler's waitcnt insertion gives MFMA-B a counted
// lgkmcnt on afb (oldest 4 reads -> lgkmcnt(8)); afn/bfn are awaited at
// their next-iter use, behind the barrier. This overlaps the ~1150-cyc LDS
// drain with the ~1240-cyc MFMA block (R3 ran them serialized: setprio
// boundaries blocked hoisting -> sum-not-max, measured 2306 cyc/step).
//
// Invariants (unchanged from R3, race-free):
//   ring of 4 slots; iter t computes slot t&3 (and reads t+1 frags), stages
//   tile t+3 into slot (t+3)&3 = slot of t-1. afb(t-1) reads complete before
//   MFMA-B(t-1) < beta(t-1) < stage issue in iter t. afn/bfn(t) complete
//   before MFMA-A(t+1) < beta(t+1) < first overwrite (stage(t+5), iter t+2).
//   vmcnt(4) at iter end: stage(t+1) landed (t+3's 4 loads may fly).
//
// T2 swizzle (BK=32, rows = 4 x 16B slots): slot' = slot ^ ((row>>1)&3),
// applied as inverse-swizzled GLOBAL source (LDS dest stays linear for
// global_load_lds) + swizzled fragment-read address (per-lane constant).
// ---------------------------------------------------------------------------
#define TBM 256
#define TBN 256
#define TBK 32
#define NT  (K_DIM / TBK)        // 128 K-steps
#define A_E 8192                 // elements of A per slot (256*32)
#define SLOT_E 16384             // elements per ring slot (A + B)

__global__ __launch_bounds__(512, 2)
void gemm_bf16_256(const ushort* __restrict__ A,
                   const ushort* __restrict__ B,
                   const float* __restrict__ bias,
                   float* __restrict__ C) {
    __shared__ ushort lds[4 * SLOT_E];   // 128 KiB -> 1 block/CU, 8 waves

    const int tid  = threadIdx.x;
    const int lane = tid & 63;
    const int wave = tid >> 6;
    const int wm   = wave >> 2;          // 0..1
    const int wn   = wave & 3;           // 0..3

    // T1: XCD-chunked bijective swizzle (nwg % 8 == 0 for both 256 and 512)
    const int nwg = gridDim.x;
    const int cpx = nwg >> 3;
    const int bid = blockIdx.x;
    const int swz = (bid & 7) * cpx + (bid >> 3);
    const int bn  = swz & (N_DIM / TBN - 1);
    const int bm  = swz / (N_DIM / TBN);

    const ushort* Ab = A + (size_t)(bm * TBM) * K_DIM;
    const ushort* Bb = B + (size_t)(bn * TBN) * K_DIM;

    // staging: thread tid covers LDS offset tid*16B of an 8KB part
    // -> part row tid>>2 (0..127); T2: fetch INVERSE-swizzled global k-chunk
    const int srow = tid >> 2;
    const int scol = (((tid & 3) ^ ((tid >> 3) & 3)) * 8);
    const ushort* gA0 = Ab + (size_t)srow * K_DIM + scol;
    const ushort* gA1 = gA0 + (size_t)128 * K_DIM;
    const ushort* gB0 = Bb + (size_t)srow * K_DIM + scol;
    const ushort* gB1 = gB0 + (size_t)128 * K_DIM;
    const int wdst = wave * 512;         // this wave's 1KB within a part

    // MFMA fragment addressing: T2 swizzled slot, constant per lane
    const int frow = lane & 15;
    const int fcol = (((lane >> 4) ^ ((frow >> 1) & 3)) * 8);
    const int aoff = (wm * 128 + frow) * TBK + fcol;          // within A region
    const int boff = A_E + (wn * 64 + frow) * TBK + fcol;     // within B region

    floatx4 acc[8][4] = {};

#define STAGE_A(tt)                                                           \
    {                                                                          \
        const int k0s = ((tt) & (NT - 1)) * TBK;                               \
        ushort* d = lds + ((tt) & 3) * SLOT_E + wdst;                          \
        __builtin_amdgcn_global_load_lds(                                      \
            (const __attribute__((address_space(1))) void*)(gA0 + k0s),        \
            (__attribute__((address_space(3))) void*)d, 16, 0, 0);             \
        __builtin_amdgcn_global_load_lds(                                      \
            (const __attribute__((address_space(1))) void*)(gA1 + k0s),        \
            (__attribute__((address_space(3))) void*)(d + 4096), 16, 0, 0);    \
    }
#define STAGE_B(tt)                                                           \
    {                                                                          \
        const int k0s = ((tt) & (NT - 1)) * TBK;                               \
        ushort* d = lds + ((tt) & 3) * SLOT_E + A_E + wdst;                    \
        __builtin_amdgcn_global_load_lds(                                      \
            (const __attribute__((address_space(1))) void*)(gB0 + k0s),        \
            (__attribute__((address_space(3))) void*)d, 16, 0, 0);             \
        __builtin_amdgcn_global_load_lds(                                      \
            (const __attribute__((address_space(1))) void*)(gB1 + k0s),        \
            (__attribute__((address_space(3))) void*)(d + 4096), 16, 0, 0);    \
    }

// one K-step; afc/bfc = current frags (consumed), afn/bfn = next frags (filled)
#define BODY(T, afc, bfc, afn, bfn)                                           \
    {                                                                          \
        const ushort* bcur = lds + ((T) & 3) * SLOT_E;                         \
        const ushort* bnxt = lds + (((T) + 1) & 3) * SLOT_E;                   \
        bf16x8 afb[4];                                                         \
        /* all 12 ds_reads up-front: afb first (oldest -> cheap counted */     \
        /* wait at MFMA-B), then next-tile bfn/afn                      */     \
        _Pragma("unroll")                                                      \
        for (int i = 0; i < 4; ++i)                                            \
            afb[i] = *(const bf16x8*)(bcur + aoff + (4 + i) * 512);            \
        _Pragma("unroll")                                                      \
        for (int j = 0; j < 4; ++j)                                            \
            bfn[j] = *(const bf16x8*)(bnxt + boff + j * 512);                  \
        _Pragma("unroll")                                                      \
        for (int i = 0; i < 4; ++i)                                            \
            afn[i] = *(const bf16x8*)(bnxt + aoff + i * 512);                  \
        STAGE_A((T) + 3) STAGE_B((T) + 3)                                      \
        __builtin_amdgcn_sched_barrier(0);                                     \
        __builtin_amdgcn_s_setprio(1);                                         \
        _Pragma("unroll")                                                      \
        for (int i = 0; i < 4; ++i)                                            \
            _Pragma("unroll")                                                  \
            for (int j = 0; j < 4; ++j)                                        \
                acc[i][j] = __builtin_amdgcn_mfma_f32_16x16x32_bf16(           \
                    afc[i], bfc[j], acc[i][j], 0, 0, 0);                       \
        _Pragma("unroll")                                                      \
        for (int i = 0; i < 4; ++i)                                            \
            _Pragma("unroll")                                                  \
            for (int j = 0; j < 4; ++j)                                        \
                acc[4 + i][j] = __builtin_amdgcn_mfma_f32_16x16x32_bf16(       \
                    afb[i], bfc[j], acc[4 + i][j], 0, 0, 0);                   \
        __builtin_amdgcn_s_setprio(0);                                         \
        asm volatile("s_waitcnt vmcnt(4)" ::: "memory");                       \
        __builtin_amdgcn_s_barrier();                                          \
        __builtin_amdgcn_sched_barrier(0);                                     \
    }

    // prologue: tiles 0,1,2 in flight; vmcnt(4) -> tiles 0,1 landed (2 flying)
    STAGE_A(0) STAGE_B(0)
    STAGE_A(1) STAGE_B(1)
    STAGE_A(2) STAGE_B(2)
    asm volatile("s_waitcnt vmcnt(4)" ::: "memory");
    __builtin_amdgcn_s_barrier();
    __builtin_amdgcn_sched_barrier(0);

    bf16x8 af0[4], bf0[4], af1[4], bf1[4];
#pragma unroll
    for (int j = 0; j < 4; ++j)
        bf0[j] = *(const bf16x8*)(lds + boff + j * 512);
#pragma unroll
    for (int i = 0; i < 4; ++i)
        af0[i] = *(const bf16x8*)(lds + aoff + i * 512);

    for (int t = 0; t < NT; t += 2) {
        BODY(t,     af0, bf0, af1, bf1)
        BODY(t + 1, af1, bf1, af0, bf0)
    }
#undef BODY
#undef STAGE_A
#undef STAGE_B

    // epilogue: C = acc + bias
    const int crow0 = bm * TBM + wm * 128;
    const int ccol0 = bn * TBN + wn * 64;
    const int rl = lane >> 4;
    const int cl = lane & 15;
#pragma unroll
    for (int j = 0; j < 4; ++j) {
        const int col = ccol0 + j * 16 + cl;
        const float bv = bias[col];
#pragma unroll
        for (int i = 0; i < 8; ++i) {
            const int row = crow0 + i * 16 + rl * 4;
            float* cp = C + (size_t)row * N_DIM + col;
#pragma unroll
            for (int r = 0; r < 4; ++r)
                cp[(size_t)r * N_DIM] = acc[i][j][r] + bv;
        }
    }
}

// ---------------------------------------------------------------------------
// Kernel 3b (fallback if ws too small): fused fp32-A GEMM, 128x128 tile.
// ---------------------------------------------------------------------------
#define BM 128
#define BN 128
#define BK 32

__global__ void gemm_fused_kernel(const float* __restrict__ X,
                                  const ushort* __restrict__ B,
                                  const float* __restrict__ bias,
                                  float* __restrict__ C) {
    __shared__ ushort As[BM * BK];
    __shared__ ushort Bs[BN * BK];

    const int tid  = threadIdx.x;
    const int lane = tid & 63;
    const int wave = tid >> 6;
    const int wm   = wave >> 1;
    const int wn   = wave & 1;
    const int bm   = blockIdx.y;
    const int bn   = blockIdx.x;

    const int ar = tid >> 2;          // 0..63
    const int ac = (tid & 3) * 8;     // k-offset (elements)
    const float* xp0 = X + (size_t)(bm * BM + ar) * K_DIM + ac;
    const float* xp1 = xp0 + (size_t)64 * K_DIM;
    ushort* as0 = As + ar * BK + ac;
    ushort* as1 = as0 + 64 * BK;

    const int scol = (lane & 3) * 8;
    const ushort* Bb = B + (size_t)(bn * BN) * K_DIM;

    floatx4 acc[4][4] = {};

    for (int k0 = 0; k0 < K_DIM; k0 += BK) {
        float4 a0 = *(const float4*)(xp0 + k0);
        float4 a1 = *(const float4*)(xp0 + k0 + 4);
        float4 b0 = *(const float4*)(xp1 + k0);
        float4 b1 = *(const float4*)(xp1 + k0 + 4);
#pragma unroll
        for (int q = 0; q < 2; ++q) {
            const int chunk = wave * 2 + q;
            const int r = chunk * 16 + (lane >> 2);
            const ushort* gb = Bb + (size_t)r * K_DIM + k0 + scol;
            __builtin_amdgcn_global_load_lds(
                (const __attribute__((address_space(1))) void*)gb,
                (__attribute__((address_space(3))) void*)(Bs + chunk * 512),
                16, 0, 0);
        }
        uint4 w0, w1;
        w0.x = pk_bf_trunc(a0.x, a0.y);
        w0.y = pk_bf_trunc(a0.z, a0.w);
        w0.z = pk_bf_trunc(a1.x, a1.y);
        w0.w = pk_bf_trunc(a1.z, a1.w);
        w1.x = pk_bf_trunc(b0.x, b0.y);
        w1.y = pk_bf_trunc(b0.z, b0.w);
        w1.z = pk_bf_trunc(b1.x, b1.y);
        w1.w = pk_bf_trunc(b1.z, b1.w);
        *(uint4*)as0 = w0;
        *(uint4*)as1 = w1;

        __syncthreads();

        bf16x8 af[4], bfr[4];
        const int frow = lane & 15;
        const int fcol = (lane >> 4) * 8;
#pragma unroll
        for (int i = 0; i < 4; ++i) {
            af[i]  = *(const bf16x8*)(As + (wm * 64 + i * 16 + frow) * BK + fcol);
            bfr[i] = *(const bf16x8*)(Bs + (wn * 64 + i * 16 + frow) * BK + fcol);
        }
#pragma unroll
        for (int i = 0; i < 4; ++i)
#pragma unroll
            for (int j = 0; j < 4; ++j)
                acc[i][j] = __builtin_amdgcn_mfma_f32_16x16x32_bf16(
                    af[i], bfr[j], acc[i][j], 0, 0, 0);
        __syncthreads();
    }

    const int crow0 = bm * BM + wm * 64;
    const int ccol0 = bn * BN + wn * 64;
    const int rl = lane >> 4;
    const int cl = lane & 15;
#pragma unroll
    for (int j = 0; j < 4; ++j) {
        const int col = ccol0 + j * 16 + cl;
        const float bv = bias[col];
#pragma unroll
        for (int i = 0; i < 4; ++i) {
            const int row = crow0 + i * 16 + rl * 4;
            float* cp = C + (size_t)row * N_DIM + col;
#pragma unroll
            for (int r = 0; r < 4; ++r)
                cp[(size_t)r * N_DIM] = acc[i][j][r] + bv;
        }
    }
}

// ---------------------------------------------------------------------------
extern "C" void kernel_launch(void* const* d_in, const int* in_sizes, int n_in,
                              void* d_out, int out_size, void* d_ws, size_t ws_size,
                              hipStream_t stream) {
    const float* x      = (const float*)d_in[0];
    const int*   pw     = (const int*)d_in[1];
    const float* scales = (const float*)d_in[2];
    const float* zps    = (const float*)d_in[3];
    const float* bias   = (const float*)d_in[4];
    float* out = (float*)d_out;

    ushort* wb = (ushort*)d_ws;                        // 33.5 MB

    {
        int np4 = (N_DIM * K_DIM / 2) / 4;
        dequant_w_kernel<<<np4 / 256, 256, 0, stream>>>(
            (const int4*)pw, scales, zps, (uint4*)wb, np4);
    }

    const size_t need_full  = ((size_t)N_DIM * K_DIM + (size_t)M_DIM * K_DIM) * 2;
    const size_t need_chunk = ((size_t)N_DIM * K_DIM + (size_t)CHUNK_M * K_DIM) * 2;

    if (ws_size >= need_full) {
        // full path: convert all of x once, single GEMM over M=8192
        ushort* xb = wb + (size_t)N_DIM * K_DIM;       // 67.1 MB
        int n4 = (M_DIM * K_DIM) / 4;
        convert_x_kernel<<<n4 / 256, 256, 0, stream>>>(
            (const float4*)x, (ushort4*)xb, n4);
        int nblk = (M_DIM / TBM) * (N_DIM / TBN);      // 32*16 = 512
        gemm_bf16_256<<<nblk, 512, 0, stream>>>(xb, wb, bias, out);
    } else if (ws_size >= need_chunk) {
        // chunked path: convert x chunk -> bf16 in ws, GEMM per chunk
        ushort* xb = wb + (size_t)N_DIM * K_DIM;       // 33.5 MB chunk buffer
        for (int c = 0; c < M_DIM / CHUNK_M; ++c) {
            const float* xc = x + (size_t)c * CHUNK_M * K_DIM;
            float* oc = out + (size_t)c * CHUNK_M * N_DIM;
            int n4 = (CHUNK_M * K_DIM) / 4;
            convert_x_kernel<<<n4 / 256, 256, 0, stream>>>(
                (const float4*)xc, (ushort4*)xb, n4);
            int nblk = (CHUNK_M / TBM) * (N_DIM / TBN);  // 16*16 = 256
            gemm_bf16_256<<<nblk, 512, 0, stream>>>(xb, wb, bias, oc);
        }
    } else {
        // fallback: fused conversion with conflict-free LDS writes
        dim3 grid(N_DIM / BN, M_DIM / BM);             // (32, 64)
        gemm_fused_kernel<<<grid, 256, 0, stream>>>(x, wb, bias, out);
    }
}

// Round 5
// 464.330 us; speedup vs baseline: 1.1889x; 1.0165x over previous
//
#include <hip/hip_runtime.h>
#include <cstdint>
#include <cstddef>

#define M_DIM 8192
#define N_DIM 4096
#define K_DIM 4096
#define CHUNK_M 4096   // chunked fallback if ws can't hold full converted x

typedef __attribute__((ext_vector_type(8))) short bf16x8;
typedef __attribute__((ext_vector_type(4))) float floatx4;

__device__ __forceinline__ ushort f2bf_rne(float f) {
    union { float f; uint32_t u; } a;
    a.f = f;
    uint32_t u = a.u;
    uint32_t r = (u + 0x7fffu + ((u >> 16) & 1u)) >> 16;
    return (ushort)r;
}

// pack two fp32 into two bf16 (truncation), 1 instr
__device__ __forceinline__ uint32_t pk_bf_trunc(float f0, float f1) {
    return __builtin_amdgcn_perm(__float_as_uint(f1), __float_as_uint(f0),
                                 0x07060302u);
}

// ---------------------------------------------------------------------------
// Kernel 1: packed int4 (one signed byte per int32) -> dequant -> bf16 (RNE)
// ---------------------------------------------------------------------------
__global__ void dequant_w_kernel(const int4* __restrict__ pw,
                                 const float* __restrict__ scales,
                                 const float* __restrict__ zps,
                                 uint4* __restrict__ wb, int np4) {
    int p4 = blockIdx.x * blockDim.x + threadIdx.x;
    if (p4 >= np4) return;
    int p = p4 * 4;
    int g = p >> 18;
    float s = scales[g];
    float b = -zps[g] * s;
    int4 v = pw[p4];
    int vv[4] = { v.x, v.y, v.z, v.w };
    ushort o[8];
#pragma unroll
    for (int j = 0; j < 4; ++j) {
        int lo = ((int)((uint32_t)vv[j] << 28)) >> 28;
        int hi = ((int)((uint32_t)vv[j] << 24)) >> 28;
        o[2 * j]     = f2bf_rne(fmaf((float)lo, s, b));
        o[2 * j + 1] = f2bf_rne(fmaf((float)hi, s, b));
    }
    uint4 st;
    st.x = (uint32_t)o[0] | ((uint32_t)o[1] << 16);
    st.y = (uint32_t)o[2] | ((uint32_t)o[3] << 16);
    st.z = (uint32_t)o[4] | ((uint32_t)o[5] << 16);
    st.w = (uint32_t)o[6] | ((uint32_t)o[7] << 16);
    wb[p4] = st;
}

// ---------------------------------------------------------------------------
// Kernel 2: x fp32 -> bf16 (RNE)
// ---------------------------------------------------------------------------
__global__ void convert_x_kernel(const float4* __restrict__ x4,
                                 ushort4* __restrict__ out4, int n4) {
    int i = blockIdx.x * blockDim.x + threadIdx.x;
    if (i >= n4) return;
    float4 v = x4[i];
    ushort4 o;
    o.x = f2bf_rne(v.x);
    o.y = f2bf_rne(v.y);
    o.z = f2bf_rne(v.z);
    o.w = f2bf_rne(v.w);
    out4[i] = o;
}

// ---------------------------------------------------------------------------
// Kernel 3a: 256x256-tile pipelined bf16 GEMM (T1+T2+T4+T5, fine interleave).
// A [M][K] bf16 row-major, B [N][K] bf16 row-major. C = A*B^T + bias.
// 512 threads = 8 waves (2M x 4N), per-wave 128x64 output, acc[8][4].
//
// R5 schedule (m201-style fine interleave; R4's bulk-issue of 12 ds_reads +
// 4 gloads flooded the LDS request queue -> waves stalled AT ISSUE before
// reaching their MFMAs -> pipes serialized, measured 2250 cyc/step = sum of
// MFMA 1242 + LDS 1150). Per K-step, per wave:
//   G1: 4 ds_read (afb = A rows4-7 of t) + STAGE_A(t+3)   | 8 MFMA (A, i=0,1)
//   G2: 4 ds_read (bfn = B of t+1)       + STAGE_B(t+3)   | 8 MFMA (A, i=2,3)
//   G3: 4 ds_read (afn = A rows0-3 of t+1)                |
//   lgkmcnt(8)  -> afb (oldest 4) landed; bfn/afn stay outstanding
//                                                          | 8 MFMA (B, i=0,1)
//                                                          | 8 MFMA (B, i=2,3)
//   vmcnt(4) -> stage(t+2) landed (t+3's 4 loads may fly); s_barrier.
// sched_barrier(0) only at group boundaries (scheduler free inside groups);
// setprio(1) around each MFMA cluster (T5).
//
// Invariants (unchanged since R3, race-free):
//   ring of 4 slots; iter t computes slot t&3 (and reads t+1 frags), stages
//   tile t+3 into slot (t+3)&3 = slot of t-1 (all reads of t-1 done before
//   beta(t-1), the barrier ending iter t-1). afn/bfn(t) complete before
//   MFMA-A(t+1) < beta(t+1) < first overwrite (stage(t+5), iter t+2).
//
// T2 swizzle (BK=32, rows = 4 x 16B slots): slot' = slot ^ ((row>>1)&3),
// applied as inverse-swizzled GLOBAL source (LDS dest stays linear for
// global_load_lds) + swizzled fragment-read address (per-lane constant).
// ---------------------------------------------------------------------------
#define TBM 256
#define TBN 256
#define TBK 32
#define NT  (K_DIM / TBK)        // 128 K-steps
#define A_E 8192                 // elements of A per slot (256*32)
#define SLOT_E 16384             // elements per ring slot (A + B)

__global__ __launch_bounds__(512, 2)
void gemm_bf16_256(const ushort* __restrict__ A,
                   const ushort* __restrict__ B,
                   const float* __restrict__ bias,
                   float* __restrict__ C) {
    __shared__ ushort lds[4 * SLOT_E];   // 128 KiB -> 1 block/CU, 8 waves

    const int tid  = threadIdx.x;
    const int lane = tid & 63;
    const int wave = tid >> 6;
    const int wm   = wave >> 2;          // 0..1
    const int wn   = wave & 3;           // 0..3

    // T1: XCD-chunked bijective swizzle (nwg % 8 == 0 for both 256 and 512)
    const int nwg = gridDim.x;
    const int cpx = nwg >> 3;
    const int bid = blockIdx.x;
    const int swz = (bid & 7) * cpx + (bid >> 3);
    const int bn  = swz & (N_DIM / TBN - 1);
    const int bm  = swz / (N_DIM / TBN);

    const ushort* Ab = A + (size_t)(bm * TBM) * K_DIM;
    const ushort* Bb = B + (size_t)(bn * TBN) * K_DIM;

    // staging: thread tid covers LDS offset tid*16B of an 8KB part
    // -> part row tid>>2 (0..127); T2: fetch INVERSE-swizzled global k-chunk
    const int srow = tid >> 2;
    const int scol = (((tid & 3) ^ ((tid >> 3) & 3)) * 8);
    const ushort* gA0 = Ab + (size_t)srow * K_DIM + scol;
    const ushort* gA1 = gA0 + (size_t)128 * K_DIM;
    const ushort* gB0 = Bb + (size_t)srow * K_DIM + scol;
    const ushort* gB1 = gB0 + (size_t)128 * K_DIM;
    const int wdst = wave * 512;         // this wave's 1KB within a part

    // MFMA fragment addressing: T2 swizzled slot, constant per lane
    const int frow = lane & 15;
    const int fcol = (((lane >> 4) ^ ((frow >> 1) & 3)) * 8);
    const int aoff = (wm * 128 + frow) * TBK + fcol;          // within A region
    const int boff = A_E + (wn * 64 + frow) * TBK + fcol;     // within B region

    floatx4 acc[8][4] = {};

#define STAGE_A(tt)                                                           \
    {                                                                          \
        const int k0s = ((tt) & (NT - 1)) * TBK;                               \
        ushort* d = lds + ((tt) & 3) * SLOT_E + wdst;                          \
        __builtin_amdgcn_global_load_lds(                                      \
            (const __attribute__((address_space(1))) void*)(gA0 + k0s),        \
            (__attribute__((address_space(3))) void*)d, 16, 0, 0);             \
        __builtin_amdgcn_global_load_lds(                                      \
            (const __attribute__((address_space(1))) void*)(gA1 + k0s),        \
            (__attribute__((address_space(3))) void*)(d + 4096), 16, 0, 0);    \
    }
#define STAGE_B(tt)                                                           \
    {                                                                          \
        const int k0s = ((tt) & (NT - 1)) * TBK;                               \
        ushort* d = lds + ((tt) & 3) * SLOT_E + A_E + wdst;                    \
        __builtin_amdgcn_global_load_lds(                                      \
            (const __attribute__((address_space(1))) void*)(gB0 + k0s),        \
            (__attribute__((address_space(3))) void*)d, 16, 0, 0);             \
        __builtin_amdgcn_global_load_lds(                                      \
            (const __attribute__((address_space(1))) void*)(gB1 + k0s),        \
            (__attribute__((address_space(3))) void*)(d + 4096), 16, 0, 0);    \
    }

// one K-step; afc/bfc = current frags (consumed), afn/bfn = next frags (filled)
#define BODY(T, afc, bfc, afn, bfn)                                           \
    {                                                                          \
        const ushort* bcur = lds + ((T) & 3) * SLOT_E;                         \
        const ushort* bnxt = lds + (((T) + 1) & 3) * SLOT_E;                   \
        bf16x8 afb[4];                                                         \
        /* G1: afb reads + stage A(t+3) */                                     \
        _Pragma("unroll")                                                      \
        for (int i = 0; i < 4; ++i)                                            \
            afb[i] = *(const bf16x8*)(bcur + aoff + (4 + i) * 512);            \
        STAGE_A((T) + 3)                                                       \
        __builtin_amdgcn_sched_barrier(0);                                     \
        __builtin_amdgcn_s_setprio(1);                                         \
        _Pragma("unroll")                                                      \
        for (int i = 0; i < 2; ++i)                                            \
            _Pragma("unroll")                                                  \
            for (int j = 0; j < 4; ++j)                                        \
                acc[i][j] = __builtin_amdgcn_mfma_f32_16x16x32_bf16(           \
                    afc[i], bfc[j], acc[i][j], 0, 0, 0);                       \
        __builtin_amdgcn_s_setprio(0);                                         \
        __builtin_amdgcn_sched_barrier(0);                                     \
        /* G2: bfn reads + stage B(t+3) */                                     \
        _Pragma("unroll")                                                      \
        for (int j = 0; j < 4; ++j)                                            \
            bfn[j] = *(const bf16x8*)(bnxt + boff + j * 512);                  \
        STAGE_B((T) + 3)                                                       \
        __builtin_amdgcn_sched_barrier(0);                                     \
        __builtin_amdgcn_s_setprio(1);                                         \
        _Pragma("unroll")                                                      \
        for (int i = 2; i < 4; ++i)                                            \
            _Pragma("unroll")                                                  \
            for (int j = 0; j < 4; ++j)                                        \
                acc[i][j] = __builtin_amdgcn_mfma_f32_16x16x32_bf16(           \
                    afc[i], bfc[j], acc[i][j], 0, 0, 0);                       \
        __builtin_amdgcn_s_setprio(0);                                         \
        __builtin_amdgcn_sched_barrier(0);                                     \
        /* G3: afn reads */                                                    \
        _Pragma("unroll")                                                      \
        for (int i = 0; i < 4; ++i)                                            \
            afn[i] = *(const bf16x8*)(bnxt + aoff + i * 512);                  \
        __builtin_amdgcn_sched_barrier(0);                                     \
        /* afb = oldest 4 of 12 outstanding ds_reads -> counted wait */        \
        asm volatile("s_waitcnt lgkmcnt(8)" ::: "memory");                     \
        __builtin_amdgcn_sched_barrier(0);                                     \
        __builtin_amdgcn_s_setprio(1);                                         \
        _Pragma("unroll")                                                      \
        for (int i = 0; i < 2; ++i)                                            \
            _Pragma("unroll")                                                  \
            for (int j = 0; j < 4; ++j)                                        \
                acc[4 + i][j] = __builtin_amdgcn_mfma_f32_16x16x32_bf16(       \
                    afb[i], bfc[j], acc[4 + i][j], 0, 0, 0);                   \
        __builtin_amdgcn_s_setprio(0);                                         \
        __builtin_amdgcn_sched_barrier(0);                                     \
        __builtin_amdgcn_s_setprio(1);                                         \
        _Pragma("unroll")                                                      \
        for (int i = 2; i < 4; ++i)                                            \
            _Pragma("unroll")                                                  \
            for (int j = 0; j < 4; ++j)                                        \
                acc[4 + i][j] = __builtin_amdgcn_mfma_f32_16x16x32_bf16(       \
                    afb[i], bfc[j], acc[4 + i][j], 0, 0, 0);                   \
        __builtin_amdgcn_s_setprio(0);                                         \
        asm volatile("s_waitcnt vmcnt(4)" ::: "memory");                       \
        __builtin_amdgcn_s_barrier();                                          \
        __builtin_amdgcn_sched_barrier(0);                                     \
    }

    // prologue: tiles 0,1,2 in flight; vmcnt(4) -> tiles 0,1 landed (2 flying)
    STAGE_A(0) STAGE_B(0)
    STAGE_A(1) STAGE_B(1)
    STAGE_A(2) STAGE_B(2)
    asm volatile("s_waitcnt vmcnt(4)" ::: "memory");
    __builtin_amdgcn_s_barrier();
    __builtin_amdgcn_sched_barrier(0);

    bf16x8 af0[4], bf0[4], af1[4], bf1[4];
#pragma unroll
    for (int j = 0; j < 4; ++j)
        bf0[j] = *(const bf16x8*)(lds + boff + j * 512);
#pragma unroll
    for (int i = 0; i < 4; ++i)
        af0[i] = *(const bf16x8*)(lds + aoff + i * 512);

    for (int t = 0; t < NT; t += 2) {
        BODY(t,     af0, bf0, af1, bf1)
        BODY(t + 1, af1, bf1, af0, bf0)
    }
#undef BODY
#undef STAGE_A
#undef STAGE_B

    // epilogue: C = acc + bias
    const int crow0 = bm * TBM + wm * 128;
    const int ccol0 = bn * TBN + wn * 64;
    const int rl = lane >> 4;
    const int cl = lane & 15;
#pragma unroll
    for (int j = 0; j < 4; ++j) {
        const int col = ccol0 + j * 16 + cl;
        const float bv = bias[col];
#pragma unroll
        for (int i = 0; i < 8; ++i) {
            const int row = crow0 + i * 16 + rl * 4;
            float* cp = C + (size_t)row * N_DIM + col;
#pragma unroll
            for (int r = 0; r < 4; ++r)
                cp[(size_t)r * N_DIM] = acc[i][j][r] + bv;
        }
    }
}

// ---------------------------------------------------------------------------
// Kernel 3b (fallback if ws too small): fused fp32-A GEMM, 128x128 tile.
// ---------------------------------------------------------------------------
#define BM 128
#define BN 128
#define BK 32

__global__ void gemm_fused_kernel(const float* __restrict__ X,
                                  const ushort* __restrict__ B,
                                  const float* __restrict__ bias,
                                  float* __restrict__ C) {
    __shared__ ushort As[BM * BK];
    __shared__ ushort Bs[BN * BK];

    const int tid  = threadIdx.x;
    const int lane = tid & 63;
    const int wave = tid >> 6;
    const int wm   = wave >> 1;
    const int wn   = wave & 1;
    const int bm   = blockIdx.y;
    const int bn   = blockIdx.x;

    const int ar = tid >> 2;          // 0..63
    const int ac = (tid & 3) * 8;     // k-offset (elements)
    const float* xp0 = X + (size_t)(bm * BM + ar) * K_DIM + ac;
    const float* xp1 = xp0 + (size_t)64 * K_DIM;
    ushort* as0 = As + ar * BK + ac;
    ushort* as1 = as0 + 64 * BK;

    const int scol = (lane & 3) * 8;
    const ushort* Bb = B + (size_t)(bn * BN) * K_DIM;

    floatx4 acc[4][4] = {};

    for (int k0 = 0; k0 < K_DIM; k0 += BK) {
        float4 a0 = *(const float4*)(xp0 + k0);
        float4 a1 = *(const float4*)(xp0 + k0 + 4);
        float4 b0 = *(const float4*)(xp1 + k0);
        float4 b1 = *(const float4*)(xp1 + k0 + 4);
#pragma unroll
        for (int q = 0; q < 2; ++q) {
            const int chunk = wave * 2 + q;
            const int r = chunk * 16 + (lane >> 2);
            const ushort* gb = Bb + (size_t)r * K_DIM + k0 + scol;
            __builtin_amdgcn_global_load_lds(
                (const __attribute__((address_space(1))) void*)gb,
                (__attribute__((address_space(3))) void*)(Bs + chunk * 512),
                16, 0, 0);
        }
        uint4 w0, w1;
        w0.x = pk_bf_trunc(a0.x, a0.y);
        w0.y = pk_bf_trunc(a0.z, a0.w);
        w0.z = pk_bf_trunc(a1.x, a1.y);
        w0.w = pk_bf_trunc(a1.z, a1.w);
        w1.x = pk_bf_trunc(b0.x, b0.y);
        w1.y = pk_bf_trunc(b0.z, b0.w);
        w1.z = pk_bf_trunc(b1.x, b1.y);
        w1.w = pk_bf_trunc(b1.z, b1.w);
        *(uint4*)as0 = w0;
        *(uint4*)as1 = w1;

        __syncthreads();

        bf16x8 af[4], bfr[4];
        const int frow = lane & 15;
        const int fcol = (lane >> 4) * 8;
#pragma unroll
        for (int i = 0; i < 4; ++i) {
            af[i]  = *(const bf16x8*)(As + (wm * 64 + i * 16 + frow) * BK + fcol);
            bfr[i] = *(const bf16x8*)(Bs + (wn * 64 + i * 16 + frow) * BK + fcol);
        }
#pragma unroll
        for (int i = 0; i < 4; ++i)
#pragma unroll
            for (int j = 0; j < 4; ++j)
                acc[i][j] = __builtin_amdgcn_mfma_f32_16x16x32_bf16(
                    af[i], bfr[j], acc[i][j], 0, 0, 0);
        __syncthreads();
    }

    const int crow0 = bm * BM + wm * 64;
    const int ccol0 = bn * BN + wn * 64;
    const int rl = lane >> 4;
    const int cl = lane & 15;
#pragma unroll
    for (int j = 0; j < 4; ++j) {
        const int col = ccol0 + j * 16 + cl;
        const float bv = bias[col];
#pragma unroll
        for (int i = 0; i < 4; ++i) {
            const int row = crow0 + i * 16 + rl * 4;
            float* cp = C + (size_t)row * N_DIM + col;
#pragma unroll
            for (int r = 0; r < 4; ++r)
                cp[(size_t)r * N_DIM] = acc[i][j][r] + bv;
        }
    }
}

// ---------------------------------------------------------------------------
extern "C" void kernel_launch(void* const* d_in, const int* in_sizes, int n_in,
                              void* d_out, int out_size, void* d_ws, size_t ws_size,
                              hipStream_t stream) {
    const float* x      = (const float*)d_in[0];
    const int*   pw     = (const int*)d_in[1];
    const float* scales = (const float*)d_in[2];
    const float* zps    = (const float*)d_in[3];
    const float* bias   = (const float*)d_in[4];
    float* out = (float*)d_out;

    ushort* wb = (ushort*)d_ws;                        // 33.5 MB

    {
        int np4 = (N_DIM * K_DIM / 2) / 4;
        dequant_w_kernel<<<np4 / 256, 256, 0, stream>>>(
            (const int4*)pw, scales, zps, (uint4*)wb, np4);
    }

    const size_t need_full  = ((size_t)N_DIM * K_DIM + (size_t)M_DIM * K_DIM) * 2;
    const size_t need_chunk = ((size_t)N_DIM * K_DIM + (size_t)CHUNK_M * K_DIM) * 2;

    if (ws_size >= need_full) {
        // full path: convert all of x once, single GEMM over M=8192
        ushort* xb = wb + (size_t)N_DIM * K_DIM;       // 67.1 MB
        int n4 = (M_DIM * K_DIM) / 4;
        convert_x_kernel<<<n4 / 256, 256, 0, stream>>>(
            (const float4*)x, (ushort4*)xb, n4);
        int nblk = (M_DIM / TBM) * (N_DIM / TBN);      // 32*16 = 512
        gemm_bf16_256<<<nblk, 512, 0, stream>>>(xb, wb, bias, out);
    } else if (ws_size >= need_chunk) {
        // chunked path: convert x chunk -> bf16 in ws, GEMM per chunk
        ushort* xb = wb + (size_t)N_DIM * K_DIM;       // 33.5 MB chunk buffer
        for (int c = 0; c < M_DIM / CHUNK_M; ++c) {
            const float* xc = x + (size_t)c * CHUNK_M * K_DIM;
            float* oc = out + (size_t)c * CHUNK_M * N_DIM;
            int n4 = (CHUNK_M * K_DIM) / 4;
            convert_x_kernel<<<n4 / 256, 256, 0, stream>>>(
                (const float4*)xc, (ushort4*)xb, n4);
            int nblk = (CHUNK_M / TBM) * (N_DIM / TBN);  // 16*16 = 256
            gemm_bf16_256<<<nblk, 512, 0, stream>>>(xb, wb, bias, oc);
        }
    } else {
        // fallback: fused conversion with conflict-free LDS writes
        dim3 grid(N_DIM / BN, M_DIM / BM);             // (32, 64)
        gemm_fused_kernel<<<grid, 256, 0, stream>>>(x, wb, bias, out);
    }
}

// Round 6
// 459.348 us; speedup vs baseline: 1.2018x; 1.0108x over previous
//
#include <hip/hip_runtime.h>
#include <cstdint>
#include <cstddef>

#define M_DIM 8192
#define N_DIM 4096
#define K_DIM 4096
#define CHUNK_M 4096   // chunked fallback if ws can't hold full converted x

typedef __attribute__((ext_vector_type(8))) short bf16x8;
typedef __attribute__((ext_vector_type(4))) float floatx4;

__device__ __forceinline__ ushort f2bf_rne(float f) {
    union { float f; uint32_t u; } a;
    a.f = f;
    uint32_t u = a.u;
    uint32_t r = (u + 0x7fffu + ((u >> 16) & 1u)) >> 16;
    return (ushort)r;
}

__device__ __forceinline__ uint32_t pk_bf_trunc(float f0, float f1) {
    return __builtin_amdgcn_perm(__float_as_uint(f1), __float_as_uint(f0),
                                 0x07060302u);
}

// ---------------------------------------------------------------------------
// Kernel 1: packed int4 -> dequant -> bf16 (RNE)
// ---------------------------------------------------------------------------
__global__ void dequant_w_kernel(const int4* __restrict__ pw,
                                 const float* __restrict__ scales,
                                 const float* __restrict__ zps,
                                 uint4* __restrict__ wb, int np4) {
    int p4 = blockIdx.x * blockDim.x + threadIdx.x;
    if (p4 >= np4) return;
    int p = p4 * 4;
    int g = p >> 18;
    float s = scales[g];
    float b = -zps[g] * s;
    int4 v = pw[p4];
    int vv[4] = { v.x, v.y, v.z, v.w };
    ushort o[8];
#pragma unroll
    for (int j = 0; j < 4; ++j) {
        int lo = ((int)((uint32_t)vv[j] << 28)) >> 28;
        int hi = ((int)((uint32_t)vv[j] << 24)) >> 28;
        o[2 * j]     = f2bf_rne(fmaf((float)lo, s, b));
        o[2 * j + 1] = f2bf_rne(fmaf((float)hi, s, b));
    }
    uint4 st;
    st.x = (uint32_t)o[0] | ((uint32_t)o[1] << 16);
    st.y = (uint32_t)o[2] | ((uint32_t)o[3] << 16);
    st.z = (uint32_t)o[4] | ((uint32_t)o[5] << 16);
    st.w = (uint32_t)o[6] | ((uint32_t)o[7] << 16);
    wb[p4] = st;
}

// ---------------------------------------------------------------------------
// Kernel 2: x fp32 -> bf16 (RNE)
// ---------------------------------------------------------------------------
__global__ void convert_x_kernel(const float4* __restrict__ x4,
                                 ushort4* __restrict__ out4, int n4) {
    int i = blockIdx.x * blockDim.x + threadIdx.x;
    if (i >= n4) return;
    float4 v = x4[i];
    ushort4 o;
    o.x = f2bf_rne(v.x);
    o.y = f2bf_rne(v.y);
    o.z = f2bf_rne(v.z);
    o.w = f2bf_rne(v.w);
    out4[i] = o;
}

// ---------------------------------------------------------------------------
// Kernel 3a: 256x256 8-phase/quadrant bf16 GEMM (m201-template port).
// A [M][K] bf16 row-major, B [N][K] bf16 row-major. C = A*B^T + bias.
// 512 threads = 8 waves. Per-wave output is SPLIT-HALVED: rows
// {wm*64..+63} U {128+wm*64..+63}, cols {wn*32..+31} U {128+wn*32..+31}
// -> quadrant q uses only one (A-half, B-half) pair, enabling progressive
// half-tile certification with counted vmcnt.
//
// BK=64, dbuf=2 (LDS 128 KiB). Per K-tile, 4 phases:
//   P1 Q0=A_lo*B_lo: 12 ds_read + stage A0(t+1); lgkm(8); bar; lgkm(0);
//      16 MFMA; vmcnt(4); bar      [vmcnt(4) -> B1(t) landed for P2]
//   P2 Q1=A_lo*B_hi:  4 ds_read + stage B0(t+1); bar; lgkm(0);
//      16 MFMA; vmcnt(4); bar      [-> A1(t) landed for P3]
//   P3 Q2=A_hi*B_lo:  8 ds_read + stage B1(t+1); bar; lgkm(0);
//      16 MFMA; bar
//   P4 Q3=A_hi*B_hi:  0 ds_read + stage A1(t+1); bar;
//      16 MFMA; vmcnt(4); bar      [-> A0,B0(t+1) landed for next P1]
// Stage issue order A0,B0,B1,A1 makes each vmcnt(4) certify exactly the
// halves the next phase reads. vmcnt never drains to 0. WAR: each half is
// staged >=3 barriers after its last LDS reader (prev tile's phase).
//
// T2 swizzle (BK=64: rows = 8 x 16B slots): slot' = slot ^ (row&7).
//  - staging: linear LDS dest (gload_lds requirement); thread tid fetches
//    global k-chunk (tid&7)^((tid>>3)&7)  [inverse-swizzled source]
//  - frag reads: column byte = (slot ^ (frow&7))*16; per-lane constants
//    col0 and col0^32 (elements) for the two 32-k slices. 8-lane read
//    groups span all 8 slots -> conflict-free.
// ---------------------------------------------------------------------------
#define TBM 256
#define TBN 256
#define TBK 64
#define NKT (K_DIM / TBK)        // 64 K-tiles
#define BUF_E 32768              // elements per dbuf buffer (A 16K + B 16K)

__global__ __launch_bounds__(512, 2)
void gemm_bf16_256(const ushort* __restrict__ A,
                   const ushort* __restrict__ B,
                   const float* __restrict__ bias,
                   float* __restrict__ C) {
    __shared__ ushort lds[2 * BUF_E];    // 128 KiB

    const int tid  = threadIdx.x;
    const int lane = tid & 63;
    const int wave = tid >> 6;
    const int wm   = wave >> 2;          // 0..1
    const int wn   = wave & 3;           // 0..3

    // T1: XCD-chunked bijective swizzle (nwg % 8 == 0)
    const int nwg = gridDim.x;
    const int cpx = nwg >> 3;
    const int bid = blockIdx.x;
    const int swz = (bid & 7) * cpx + (bid >> 3);
    const int bn  = swz & (N_DIM / TBN - 1);
    const int bm  = swz / (N_DIM / TBN);

    const ushort* Ab = A + (size_t)(bm * TBM) * K_DIM;
    const ushort* Bb = B + (size_t)(bn * TBN) * K_DIM;

    // staging source: row r0 = tid>>3, inverse-swizzled k-chunk
    const int r0 = tid >> 3;
    const int kc = ((tid & 7) ^ (r0 & 7)) * 8;
    const ushort* gA = Ab + (size_t)r0 * K_DIM + kc;
    const ushort* gB = Bb + (size_t)r0 * K_DIM + kc;
    const int sdst = tid * 8;            // this thread's 16B within a gload

    // frag read bases (elements). Region layout per buffer:
    //   A at +0 (256 rows x 64), B at +16384. Row stride 64 elements.
    const int frow = lane & 15;
    const int col0 = (((lane >> 4) ^ (frow & 7)) * 8);
    const int lbA = wm * 4096 + frow * 64;           // A_lo row base
    const int lbB = 16384 + wn * 2048 + frow * 64;   // B_lo row base
    const int colx[2] = { col0, col0 ^ 32 };         // k-slice 0 / 1

    floatx4 acc[8][4] = {};

#define STAGE(SBUF, TS, OFFE, ROWOFF)                                         \
    {                                                                          \
        const int k0s = ((TS) & (NKT - 1)) * TBK;                              \
        ushort* d = (ushort*)lds + (SBUF) * BUF_E + (OFFE) + sdst;             \
        const ushort* g = ((OFFE) >= 16384 ? gB : gA);                         \
        __builtin_amdgcn_global_load_lds(                                      \
            (const __attribute__((address_space(1))) void*)                    \
                (g + (size_t)(ROWOFF) * K_DIM + k0s),                          \
            (__attribute__((address_space(3))) void*)d, 16, 0, 0);             \
        __builtin_amdgcn_global_load_lds(                                      \
            (const __attribute__((address_space(1))) void*)                    \
                (g + (size_t)((ROWOFF) + 64) * K_DIM + k0s),                   \
            (__attribute__((address_space(3))) void*)(d + 4096), 16, 0, 0);    \
    }
// halves: A0: OFFE 0 ROWOFF 0 | A1: OFFE 8192 ROWOFF 128
//         B0: OFFE 16384 ROWOFF 0 | B1: OFFE 24576 ROWOFF 128

#define MFMA_Q(ILO, AFR, JLO, BFR)                                            \
    _Pragma("unroll")                                                          \
    for (int i = 0; i < 4; ++i)                                                \
        _Pragma("unroll")                                                      \
        for (int j = 0; j < 2; ++j)                                            \
            _Pragma("unroll")                                                  \
            for (int ks = 0; ks < 2; ++ks)                                     \
                acc[(ILO) + i][(JLO) + j] =                                    \
                    __builtin_amdgcn_mfma_f32_16x16x32_bf16(                   \
                        AFR[i][ks], BFR[j][ks], acc[(ILO) + i][(JLO) + j],     \
                        0, 0, 0);

#define TILE(T, CBUF)                                                         \
    {                                                                          \
        bf16x8 alo[4][2], ahi[4][2], blo[2][2], bhi[2][2];                     \
        /* ---- P1: Q0 ---- */                                                 \
        _Pragma("unroll")                                                      \
        for (int i = 0; i < 4; ++i)                                            \
            _Pragma("unroll")                                                  \
            for (int ks = 0; ks < 2; ++ks)                                     \
                alo[i][ks] = *(const bf16x8*)(lds + (CBUF) * BUF_E + lbA +     \
                                              i * 1024 + colx[ks]);            \
        _Pragma("unroll")                                                      \
        for (int j = 0; j < 2; ++j)                                            \
            _Pragma("unroll")                                                  \
            for (int ks = 0; ks < 2; ++ks)                                     \
                blo[j][ks] = *(const bf16x8*)(lds + (CBUF) * BUF_E + lbB +     \
                                              j * 1024 + colx[ks]);            \
        STAGE((CBUF) ^ 1, (T) + 1, 0, 0)                                       \
        asm volatile("s_waitcnt lgkmcnt(8)" ::: "memory");                     \
        __builtin_amdgcn_s_barrier();                                          \
        asm volatile("s_waitcnt lgkmcnt(0)" ::: "memory");                     \
        __builtin_amdgcn_sched_barrier(0);                                     \
        __builtin_amdgcn_s_setprio(1);                                         \
        MFMA_Q(0, alo, 0, blo)                                                 \
        __builtin_amdgcn_s_setprio(0);                                         \
        asm volatile("s_waitcnt vmcnt(4)" ::: "memory");                       \
        __builtin_amdgcn_s_barrier();                                          \
        __builtin_amdgcn_sched_barrier(0);                                     \
        /* ---- P2: Q1 ---- */                                                 \
        _Pragma("unroll")                                                      \
        for (int j = 0; j < 2; ++j)                                            \
            _Pragma("unroll")                                                  \
            for (int ks = 0; ks < 2; ++ks)                                     \
                bhi[j][ks] = *(const bf16x8*)(lds + (CBUF) * BUF_E + lbB +     \
                                              8192 + j * 1024 + colx[ks]);     \
        STAGE((CBUF) ^ 1, (T) + 1, 16384, 0)                                   \
        __builtin_amdgcn_s_barrier();                                          \
        asm volatile("s_waitcnt lgkmcnt(0)" ::: "memory");                     \
        __builtin_amdgcn_sched_barrier(0);                                     \
        __builtin_amdgcn_s_setprio(1);                                         \
        MFMA_Q(0, alo, 2, bhi)                                                 \
        __builtin_amdgcn_s_setprio(0);                                         \
        asm volatile("s_waitcnt vmcnt(4)" ::: "memory");                       \
        __builtin_amdgcn_s_barrier();                                          \
        __builtin_amdgcn_sched_barrier(0);                                     \
        /* ---- P3: Q2 ---- */                                                 \
        _Pragma("unroll")                                                      \
        for (int i = 0; i < 4; ++i)                                            \
            _Pragma("unroll")                                                  \
            for (int ks = 0; ks < 2; ++ks)                                     \
                ahi[i][ks] = *(const bf16x8*)(lds + (CBUF) * BUF_E + lbA +     \
                                              8192 + i * 1024 + colx[ks]);     \
        STAGE((CBUF) ^ 1, (T) + 1, 24576, 128)                                 \
        __builtin_amdgcn_s_barrier();                                          \
        asm volatile("s_waitcnt lgkmcnt(0)" ::: "memory");                     \
        __builtin_amdgcn_sched_barrier(0);                                     \
        __builtin_amdgcn_s_setprio(1);                                         \
        MFMA_Q(4, ahi, 0, blo)                                                 \
        __builtin_amdgcn_s_setprio(0);                                         \
        __builtin_amdgcn_s_barrier();                                          \
        __builtin_amdgcn_sched_barrier(0);                                     \
        /* ---- P4: Q3 ---- */                                                 \
        STAGE((CBUF) ^ 1, (T) + 1, 8192, 128)                                  \
        __builtin_amdgcn_s_barrier();                                          \
        __builtin_amdgcn_sched_barrier(0);                                     \
        __builtin_amdgcn_s_setprio(1);                                         \
        MFMA_Q(4, ahi, 2, bhi)                                                 \
        __builtin_amdgcn_s_setprio(0);                                         \
        asm volatile("s_waitcnt vmcnt(4)" ::: "memory");                       \
        __builtin_amdgcn_s_barrier();                                          \
        __builtin_amdgcn_sched_barrier(0);                                     \
    }

    // prologue: tile 0 halves in steady-state issue order A0,B0,B1,A1;
    // vmcnt(4) -> A0,B0 landed (B1,A1 may fly) = P1's precondition.
    STAGE(0, 0, 0, 0)          // A0
    STAGE(0, 0, 16384, 0)      // B0
    STAGE(0, 0, 24576, 128)    // B1
    STAGE(0, 0, 8192, 128)     // A1
    asm volatile("s_waitcnt vmcnt(4)" ::: "memory");
    __builtin_amdgcn_s_barrier();
    __builtin_amdgcn_sched_barrier(0);

    for (int t = 0; t < NKT; t += 2) {
        TILE(t, 0)
        TILE(t + 1, 1)
    }
#undef TILE
#undef MFMA_Q
#undef STAGE

    // epilogue: C = acc + bias (split-half row/col mapping)
    const int rl = lane >> 4;
    const int cl = lane & 15;
#pragma unroll
    for (int j = 0; j < 4; ++j) {
        const int col = bn * TBN +
                        (j < 2 ? wn * 32 + j * 16 : 128 + wn * 32 + (j - 2) * 16) +
                        cl;
        const float bv = bias[col];
#pragma unroll
        for (int i = 0; i < 8; ++i) {
            const int row = bm * TBM +
                            (i < 4 ? wm * 64 + i * 16
                                   : 128 + wm * 64 + (i - 4) * 16) +
                            rl * 4;
            float* cp = C + (size_t)row * N_DIM + col;
#pragma unroll
            for (int r = 0; r < 4; ++r)
                cp[(size_t)r * N_DIM] = acc[i][j][r] + bv;
        }
    }
}

// ---------------------------------------------------------------------------
// Kernel 3b (fallback if ws too small): fused fp32-A GEMM, 128x128 tile.
// ---------------------------------------------------------------------------
#define BM 128
#define BN 128
#define BK 32

__global__ void gemm_fused_kernel(const float* __restrict__ X,
                                  const ushort* __restrict__ B,
                                  const float* __restrict__ bias,
                                  float* __restrict__ C) {
    __shared__ ushort As[BM * BK];
    __shared__ ushort Bs[BN * BK];

    const int tid  = threadIdx.x;
    const int lane = tid & 63;
    const int wave = tid >> 6;
    const int wm   = wave >> 1;
    const int wn   = wave & 1;
    const int bm   = blockIdx.y;
    const int bn   = blockIdx.x;

    const int ar = tid >> 2;
    const int ac = (tid & 3) * 8;
    const float* xp0 = X + (size_t)(bm * BM + ar) * K_DIM + ac;
    const float* xp1 = xp0 + (size_t)64 * K_DIM;
    ushort* as0 = As + ar * BK + ac;
    ushort* as1 = as0 + 64 * BK;

    const int scol = (lane & 3) * 8;
    const ushort* Bb = B + (size_t)(bn * BN) * K_DIM;

    floatx4 acc[4][4] = {};

    for (int k0 = 0; k0 < K_DIM; k0 += BK) {
        float4 a0 = *(const float4*)(xp0 + k0);
        float4 a1 = *(const float4*)(xp0 + k0 + 4);
        float4 b0 = *(const float4*)(xp1 + k0);
        float4 b1 = *(const float4*)(xp1 + k0 + 4);
#pragma unroll
        for (int q = 0; q < 2; ++q) {
            const int chunk = wave * 2 + q;
            const int r = chunk * 16 + (lane >> 2);
            const ushort* gb = Bb + (size_t)r * K_DIM + k0 + scol;
            __builtin_amdgcn_global_load_lds(
                (const __attribute__((address_space(1))) void*)gb,
                (__attribute__((address_space(3))) void*)(Bs + chunk * 512),
                16, 0, 0);
        }
        uint4 w0, w1;
        w0.x = pk_bf_trunc(a0.x, a0.y);
        w0.y = pk_bf_trunc(a0.z, a0.w);
        w0.z = pk_bf_trunc(a1.x, a1.y);
        w0.w = pk_bf_trunc(a1.z, a1.w);
        w1.x = pk_bf_trunc(b0.x, b0.y);
        w1.y = pk_bf_trunc(b0.z, b0.w);
        w1.z = pk_bf_trunc(b1.x, b1.y);
        w1.w = pk_bf_trunc(b1.z, b1.w);
        *(uint4*)as0 = w0;
        *(uint4*)as1 = w1;

        __syncthreads();

        bf16x8 af[4], bfr[4];
        const int frow = lane & 15;
        const int fcol = (lane >> 4) * 8;
#pragma unroll
        for (int i = 0; i < 4; ++i) {
            af[i]  = *(const bf16x8*)(As + (wm * 64 + i * 16 + frow) * BK + fcol);
            bfr[i] = *(const bf16x8*)(Bs + (wn * 64 + i * 16 + frow) * BK + fcol);
        }
#pragma unroll
        for (int i = 0; i < 4; ++i)
#pragma unroll
            for (int j = 0; j < 4; ++j)
                acc[i][j] = __builtin_amdgcn_mfma_f32_16x16x32_bf16(
                    af[i], bfr[j], acc[i][j], 0, 0, 0);
        __syncthreads();
    }

    const int crow0 = bm * BM + wm * 64;
    const int ccol0 = bn * BN + wn * 64;
    const int rl = lane >> 4;
    const int cl = lane & 15;
#pragma unroll
    for (int j = 0; j < 4; ++j) {
        const int col = ccol0 + j * 16 + cl;
        const float bv = bias[col];
#pragma unroll
        for (int i = 0; i < 4; ++i) {
            const int row = crow0 + i * 16 + rl * 4;
            float* cp = C + (size_t)row * N_DIM + col;
#pragma unroll
            for (int r = 0; r < 4; ++r)
                cp[(size_t)r * N_DIM] = acc[i][j][r] + bv;
        }
    }
}

// ---------------------------------------------------------------------------
extern "C" void kernel_launch(void* const* d_in, const int* in_sizes, int n_in,
                              void* d_out, int out_size, void* d_ws, size_t ws_size,
                              hipStream_t stream) {
    const float* x      = (const float*)d_in[0];
    const int*   pw     = (const int*)d_in[1];
    const float* scales = (const float*)d_in[2];
    const float* zps    = (const float*)d_in[3];
    const float* bias   = (const float*)d_in[4];
    float* out = (float*)d_out;

    ushort* wb = (ushort*)d_ws;                        // 33.5 MB

    {
        int np4 = (N_DIM * K_DIM / 2) / 4;
        dequant_w_kernel<<<np4 / 256, 256, 0, stream>>>(
            (const int4*)pw, scales, zps, (uint4*)wb, np4);
    }

    const size_t need_full  = ((size_t)N_DIM * K_DIM + (size_t)M_DIM * K_DIM) * 2;
    const size_t need_chunk = ((size_t)N_DIM * K_DIM + (size_t)CHUNK_M * K_DIM) * 2;

    if (ws_size >= need_full) {
        // full path: convert all of x once, single GEMM over M=8192
        ushort* xb = wb + (size_t)N_DIM * K_DIM;       // 67.1 MB
        int n4 = (M_DIM * K_DIM) / 4;
        convert_x_kernel<<<n4 / 256, 256, 0, stream>>>(
            (const float4*)x, (ushort4*)xb, n4);
        int nblk = (M_DIM / TBM) * (N_DIM / TBN);      // 32*16 = 512
        gemm_bf16_256<<<nblk, 512, 0, stream>>>(xb, wb, bias, out);
    } else if (ws_size >= need_chunk) {
        // chunked path
        ushort* xb = wb + (size_t)N_DIM * K_DIM;
        for (int c = 0; c < M_DIM / CHUNK_M; ++c) {
            const float* xc = x + (size_t)c * CHUNK_M * K_DIM;
            float* oc = out + (size_t)c * CHUNK_M * N_DIM;
            int n4 = (CHUNK_M * K_DIM) / 4;
            convert_x_kernel<<<n4 / 256, 256, 0, stream>>>(
                (const float4*)xc, (ushort4*)xb, n4);
            int nblk = (CHUNK_M / TBM) * (N_DIM / TBN);
            gemm_bf16_256<<<nblk, 512, 0, stream>>>(xb, wb, bias, oc);
        }
    } else {
        // fallback: fused conversion
        dim3 grid(N_DIM / BN, M_DIM / BM);
        gemm_fused_kernel<<<grid, 256, 0, stream>>>(x, wb, bias, out);
    }
}